// Round 1
// baseline (619.675 us; speedup 1.0000x reference)
//
#include <hip/hip_runtime.h>
#include <hip/hip_fp8.h>

#define M_DIM 16384
#define N_DIM 4096
#define K_DIM 2048

typedef float floatx4 __attribute__((ext_vector_type(4)));

__device__ __forceinline__ unsigned char f32_to_fp8(float v) {
    __hip_fp8_e4m3 t(v);
    return t.__x;
}

__device__ __forceinline__ float fp8_roundtrip(float v) {
    __hip_fp8_e4m3 t(v);
    return (float)t;
}

// async global->LDS, 16B per lane. LDS dest must be wave-uniform base; HW adds lane*16.
__device__ __forceinline__ void async16(const void* g, void* l) {
    __builtin_amdgcn_global_load_lds((__attribute__((address_space(1))) void*)g,
                                     (__attribute__((address_space(3))) void*)l,
                                     16, 0, 0);
}

// ---- quantize: out[i] = e4m3fn(clamp(in[i]*s, -0.5, 0.5)), 8 elems/thread ----
__global__ void quant_kernel(const float* __restrict__ in, unsigned char* __restrict__ out,
                             const float* __restrict__ sp) {
    size_t i = ((size_t)blockIdx.x * blockDim.x + threadIdx.x) * 8;
    const float s = sp ? *sp : 1.0f;
    float f[8];
    *(float4*)(f)     = *(const float4*)(in + i);
    *(float4*)(f + 4) = *(const float4*)(in + i + 4);
    unsigned long long r = 0;
#pragma unroll
    for (int j = 0; j < 8; ++j) {
        float v = fminf(fmaxf(f[j] * s, -0.5f), 0.5f);
        r |= (unsigned long long)f32_to_fp8(v) << (8 * j);
    }
    *(unsigned long long*)(out + i) = r;
}

// ---- fp8 GEMM, m97 structure: 128x128 tile, BK=64, 4 waves (2x2), 16x16x32 fp8 MFMA ----
// qA: [M,K] fp8 row-major; qB: [N,K] fp8 row-major (B^T input / NT gemm)
__global__ __launch_bounds__(256) void gemm_fp8_kernel(
        const unsigned char* __restrict__ qA, const unsigned char* __restrict__ qB,
        const float* __restrict__ bias, float* __restrict__ out) {
    __shared__ unsigned char Al[128 * 64];   // 8 KB, [row][k] linear (global_load_lds needs linear dest)
    __shared__ unsigned char Bl[128 * 64];   // 8 KB

    const int tid  = threadIdx.x;
    const int lane = tid & 63;
    const int wid  = tid >> 6;

    // XCD-aware swizzle: 4096 blocks % 8 == 0 -> simple form is bijective
    const int nwg = gridDim.x;
    const int cpx = nwg >> 3;
    const int bid = blockIdx.x;
    const int swz = (bid & 7) * cpx + (bid >> 3);
    const int bm = swz & 127;            // M/128 = 128 tiles
    const int bn = swz >> 7;             // N/128 = 32 tiles
    const size_t brow = (size_t)bm * 128;
    const size_t bcol = (size_t)bn * 128;

    // staging: per instr, each wave covers 1KB of LDS = 16 rows x 64B
    const int srow = wid * 16 + (lane >> 2);
    const int scol = (lane & 3) * 16;
    const unsigned char* ga0 = qA + (brow + srow) * K_DIM + scol;
    const unsigned char* ga1 = ga0 + (size_t)64 * K_DIM;
    const unsigned char* gb0 = qB + (bcol + srow) * K_DIM + scol;
    const unsigned char* gb1 = gb0 + (size_t)64 * K_DIM;
    unsigned char* la0 = Al + wid * 1024;           // wave-uniform
    unsigned char* la1 = Al + 4096 + wid * 1024;
    unsigned char* lb0 = Bl + wid * 1024;
    unsigned char* lb1 = Bl + 4096 + wid * 1024;

    const int wr = (wid >> 1) * 64;      // wave's output sub-tile origin
    const int wc = (wid & 1) * 64;
    const int fr = lane & 15;            // fragment row/col
    const int kg = (lane >> 4) * 8;      // k-group byte offset

    floatx4 acc[4][4] = {};              // 4 mi x 4 ni, 64 VGPRs

    for (int kt = 0; kt < K_DIM; kt += 64) {
        async16(ga0 + kt, la0);
        async16(ga1 + kt, la1);
        async16(gb0 + kt, lb0);
        async16(gb1 + kt, lb1);
        __syncthreads();                 // compiler drains vmcnt before barrier
#pragma unroll
        for (int kk = 0; kk < 2; ++kk) {
            long af[4], bf[4];
#pragma unroll
            for (int i = 0; i < 4; ++i)
                af[i] = *(const long*)(Al + (wr + i * 16 + fr) * 64 + kk * 32 + kg);
#pragma unroll
            for (int i = 0; i < 4; ++i)
                bf[i] = *(const long*)(Bl + (wc + i * 16 + fr) * 64 + kk * 32 + kg);
#pragma unroll
            for (int mi = 0; mi < 4; ++mi)
#pragma unroll
                for (int ni = 0; ni < 4; ++ni)
                    acc[mi][ni] = __builtin_amdgcn_mfma_f32_16x16x32_fp8_fp8(
                        af[mi], bf[ni], acc[mi][ni], 0, 0, 0);
        }
        __syncthreads();                 // protect LDS from next stage
    }

    // epilogue: C/D layout col=lane&15, row=(lane>>4)*4+reg (dtype-independent, m89)
    const int orow0 = (int)brow + wr + ((lane >> 4) << 2);
    const int ocol0 = (int)bcol + wc + fr;
#pragma unroll
    for (int ni = 0; ni < 4; ++ni) {
        const int oc = ocol0 + ni * 16;
        const float bv = bias[oc];
#pragma unroll
        for (int mi = 0; mi < 4; ++mi) {
#pragma unroll
            for (int j = 0; j < 4; ++j) {
                out[(size_t)(orow0 + mi * 16 + j) * N_DIM + oc] =
                    fp8_roundtrip(acc[mi][ni][j]) + bv;
            }
        }
    }
}

// ---- fallback (only if ws_size too small): 1 thread per output, exact fp32 accumulation ----
__global__ void naive_kernel(const float* __restrict__ x, const float* __restrict__ w,
                             const float* __restrict__ bias, const float* __restrict__ sp,
                             float* __restrict__ out) {
    const int ncol = blockIdx.x * blockDim.x + threadIdx.x;
    const int m = blockIdx.y;
    const float s = *sp;
    float acc = 0.f;
    for (int k = 0; k < K_DIM; ++k) {
        float q = fp8_roundtrip(fminf(fmaxf(x[(size_t)m * K_DIM + k] * s, -0.5f), 0.5f));
        acc += q * w[(size_t)ncol * K_DIM + k];   // w already on fp8 grid
    }
    out[(size_t)m * N_DIM + ncol] = fp8_roundtrip(acc) + bias[ncol];
}

extern "C" void kernel_launch(void* const* d_in, const int* in_sizes, int n_in,
                              void* d_out, int out_size, void* d_ws, size_t ws_size,
                              hipStream_t stream) {
    const float* x     = (const float*)d_in[0];
    const float* w     = (const float*)d_in[1];
    const float* bias  = (const float*)d_in[2];
    const float* scale = (const float*)d_in[3];
    float* out = (float*)d_out;

    const size_t needA = (size_t)M_DIM * K_DIM;   // 33.5 MB fp8
    const size_t needB = (size_t)N_DIM * K_DIM;   //  8.4 MB fp8

    if (ws_size >= needA + needB) {
        unsigned char* qA = (unsigned char*)d_ws;
        unsigned char* qB = qA + needA;
        quant_kernel<<<(M_DIM * K_DIM) / (256 * 8), 256, 0, stream>>>(x, qA, scale);
        quant_kernel<<<(N_DIM * K_DIM) / (256 * 8), 256, 0, stream>>>(w, qB, nullptr);
        gemm_fp8_kernel<<<(M_DIM / 128) * (N_DIM / 128), 256, 0, stream>>>(qA, qB, bias, out);
    } else {
        dim3 g(N_DIM / 256, M_DIM);
        naive_kernel<<<g, 256, 0, stream>>>(x, w, bias, scale, out);
    }
}

// Round 2
// 294.477 us; speedup vs baseline: 2.1043x; 2.1043x over previous
//
#include <hip/hip_runtime.h>
#include <hip/hip_fp8.h>

#define M_DIM 16384
#define N_DIM 4096
#define K_DIM 2048
#define NKT   (K_DIM / 64)   // 32 K-tiles of 64

typedef float floatx4 __attribute__((ext_vector_type(4)));
typedef long  longx2  __attribute__((ext_vector_type(2)));

__device__ __forceinline__ unsigned char f32_to_fp8(float v) {
    __hip_fp8_e4m3 t(v);
    return t.__x;
}

__device__ __forceinline__ float fp8_roundtrip(float v) {
    __hip_fp8_e4m3 t(v);
    return (float)t;
}

// async global->LDS, 16B per lane. LDS dest is wave-uniform base + lane*16.
__device__ __forceinline__ void async16(const void* g, void* l) {
    __builtin_amdgcn_global_load_lds((__attribute__((address_space(1))) void*)g,
                                     (__attribute__((address_space(3))) void*)l,
                                     16, 0, 0);
}

// ---- quantize + pack into MFMA-fragment order ----
// Packed layout (per 16-row x 64-k sub-block of 1024B):
//   chunk index p -> (rb = p>>11, kt = (p>>6)&31, l16 = p&63)
//   l16 = kgi*16 + r_local; chunk bytes [0..7] = k = kt*64 + kgi*8 + b   (kk=0)
//                           chunk bytes [8..15] = k = kt*64 + 32 + kgi*8 + b (kk=1)
// so in the GEMM, lane l of a wave reads its exact 16x16x32-fp8 A/B fragment pair
// (row = l&15, kgroup = l>>4, both kk halves) at lds_base + s*1024 + l*16.
__global__ void quant_pack_kernel(const float* __restrict__ in,
                                  unsigned char* __restrict__ out,
                                  const float* __restrict__ sp) {
    const int p = blockIdx.x * blockDim.x + threadIdx.x;  // one 16B packed chunk
    const float s = sp ? *sp : 1.0f;
    const int l16     = p & 63;
    const int chunk   = p >> 6;
    const int kt      = chunk & (NKT - 1);
    const int rb      = chunk >> 5;            // log2(NKT) = 5
    const int r_local = l16 & 15;
    const int kgi     = l16 >> 4;
    const size_t m  = (size_t)rb * 16 + r_local;
    const int    k0 = kt * 64 + kgi * 8;
    const float* src = in + m * K_DIM + k0;
    float f[16];
    *(float4*)(f)      = *(const float4*)(src);        // k0..k0+3
    *(float4*)(f + 4)  = *(const float4*)(src + 4);    // k0+4..k0+7
    *(float4*)(f + 8)  = *(const float4*)(src + 32);   // kk=1 half
    *(float4*)(f + 12) = *(const float4*)(src + 36);
    unsigned long long lo = 0, hi = 0;
#pragma unroll
    for (int j = 0; j < 8; ++j) {
        float v0 = fminf(fmaxf(f[j] * s, -0.5f), 0.5f);
        float v1 = fminf(fmaxf(f[j + 8] * s, -0.5f), 0.5f);
        lo |= (unsigned long long)f32_to_fp8(v0) << (8 * j);
        hi |= (unsigned long long)f32_to_fp8(v1) << (8 * j);
    }
    unsigned long long* dst = (unsigned long long*)(out + (size_t)p * 16);
    dst[0] = lo;
    dst[1] = hi;
}

// ---- fp8 GEMM: 128x128 tile, BK=64, 4 waves (2x2), 16x16x32 fp8 MFMA ----
// qA/qB are fragment-packed (see above). Staging is identity (lane-linear 16B),
// fragment reads are lane-linear ds_read_b128 -> zero bank conflicts.
__global__ __launch_bounds__(256) void gemm_fp8_kernel(
        const unsigned char* __restrict__ qA, const unsigned char* __restrict__ qB,
        const float* __restrict__ bias, float* __restrict__ out) {
    __shared__ unsigned char Al[8 * 1024];   // 8 sub-blocks of 16 rows x 64 k
    __shared__ unsigned char Bl[8 * 1024];

    const int tid  = threadIdx.x;
    const int lane = tid & 63;
    const int wid  = tid >> 6;

    // XCD-aware swizzle: 4096 blocks % 8 == 0 -> bijective simple form
    const int cpx = gridDim.x >> 3;
    const int swz = (blockIdx.x & 7) * cpx + (blockIdx.x >> 3);
    const int bm = swz & 127;            // M/128 = 128 tiles
    const int bn = swz >> 7;             // N/128 = 32 tiles

    // staging: wave wid fills sub-blocks wid (rows wid*16..) and wid+4
    const size_t a_rb0 = (size_t)bm * 8 + wid;
    const size_t b_rb0 = (size_t)bn * 8 + wid;
    const unsigned char* ga0 = qA + (a_rb0 << 15) + (lane << 4);  // rb*NKT*1024 = rb<<15
    const unsigned char* ga1 = ga0 + (4ull << 15);
    const unsigned char* gb0 = qB + (b_rb0 << 15) + (lane << 4);
    const unsigned char* gb1 = gb0 + (4ull << 15);
    unsigned char* la0 = Al + wid * 1024;            // wave-uniform dest
    unsigned char* la1 = Al + (4 + wid) * 1024;
    unsigned char* lb0 = Bl + wid * 1024;
    unsigned char* lb1 = Bl + (4 + wid) * 1024;

    // compute: wave (wid>>1, wid&1) owns 64x64 output sub-tile
    const int sA = (wid >> 1) * 4;       // A sub-block base
    const int sB = (wid & 1) * 4;
    const int wr = (wid >> 1) * 64;
    const int wc = (wid & 1) * 64;
    const int fr = lane & 15;

    floatx4 acc[4][4] = {};

    for (int kt = 0; kt < NKT; ++kt) {
        const int ko = kt << 10;
        async16(ga0 + ko, la0);
        async16(ga1 + ko, la1);
        async16(gb0 + ko, lb0);
        async16(gb1 + ko, lb1);
        __syncthreads();                 // compiler drains vmcnt before barrier

        longx2 a[4], b[4];
#pragma unroll
        for (int i = 0; i < 4; ++i)
            a[i] = *(const longx2*)(Al + (sA + i) * 1024 + lane * 16);
#pragma unroll
        for (int i = 0; i < 4; ++i)
            b[i] = *(const longx2*)(Bl + (sB + i) * 1024 + lane * 16);
#pragma unroll
        for (int mi = 0; mi < 4; ++mi)
#pragma unroll
            for (int ni = 0; ni < 4; ++ni)
                acc[mi][ni] = __builtin_amdgcn_mfma_f32_16x16x32_fp8_fp8(
                    a[mi].x, b[ni].x, acc[mi][ni], 0, 0, 0);
#pragma unroll
        for (int mi = 0; mi < 4; ++mi)
#pragma unroll
            for (int ni = 0; ni < 4; ++ni)
                acc[mi][ni] = __builtin_amdgcn_mfma_f32_16x16x32_fp8_fp8(
                    a[mi].y, b[ni].y, acc[mi][ni], 0, 0, 0);
        __syncthreads();                 // protect LDS before next stage
    }

    // epilogue: C/D layout col=lane&15, row=(lane>>4)*4+reg (dtype-independent, m89)
    const int orow0 = bm * 128 + wr + ((lane >> 4) << 2);
    const int ocol0 = bn * 128 + wc + fr;
#pragma unroll
    for (int ni = 0; ni < 4; ++ni) {
        const int oc = ocol0 + ni * 16;
        const float bv = bias[oc];
#pragma unroll
        for (int mi = 0; mi < 4; ++mi) {
#pragma unroll
            for (int j = 0; j < 4; ++j) {
                out[(size_t)(orow0 + mi * 16 + j) * N_DIM + oc] =
                    fp8_roundtrip(acc[mi][ni][j]) + bv;
            }
        }
    }
}

// ---- fallback (only if ws too small): 1 thread per output, exact fp32 accumulation ----
__global__ void naive_kernel(const float* __restrict__ x, const float* __restrict__ w,
                             const float* __restrict__ bias, const float* __restrict__ sp,
                             float* __restrict__ out) {
    const int ncol = blockIdx.x * blockDim.x + threadIdx.x;
    const int m = blockIdx.y;
    const float s = *sp;
    float acc = 0.f;
    for (int k = 0; k < K_DIM; ++k) {
        float q = fp8_roundtrip(fminf(fmaxf(x[(size_t)m * K_DIM + k] * s, -0.5f), 0.5f));
        acc += q * w[(size_t)ncol * K_DIM + k];
    }
    out[(size_t)m * N_DIM + ncol] = fp8_roundtrip(acc) + bias[ncol];
}

extern "C" void kernel_launch(void* const* d_in, const int* in_sizes, int n_in,
                              void* d_out, int out_size, void* d_ws, size_t ws_size,
                              hipStream_t stream) {
    const float* x     = (const float*)d_in[0];
    const float* w     = (const float*)d_in[1];
    const float* bias  = (const float*)d_in[2];
    const float* scale = (const float*)d_in[3];
    float* out = (float*)d_out;

    const size_t needA = (size_t)M_DIM * K_DIM;   // 33.5 MB fp8
    const size_t needB = (size_t)N_DIM * K_DIM;   //  8.4 MB fp8

    if (ws_size >= needA + needB) {
        unsigned char* qA = (unsigned char*)d_ws;
        unsigned char* qB = qA + needA;
        quant_pack_kernel<<<(M_DIM * K_DIM / 16) / 256, 256, 0, stream>>>(x, qA, scale);
        quant_pack_kernel<<<(N_DIM * K_DIM / 16) / 256, 256, 0, stream>>>(w, qB, nullptr);
        gemm_fp8_kernel<<<(M_DIM / 128) * (N_DIM / 128), 256, 0, stream>>>(qA, qB, bias, out);
    } else {
        dim3 g(N_DIM / 256, M_DIM);
        naive_kernel<<<g, 256, 0, stream>>>(x, w, bias, scale, out);
    }
}

// Round 3
// 271.032 us; speedup vs baseline: 2.2863x; 1.0865x over previous
//
#include <hip/hip_runtime.h>
#include <hip/hip_fp8.h>

#define M_DIM 16384
#define N_DIM 4096
#define K_DIM 2048
#define NKT   (K_DIM / 128)   // 16 K-tiles of 128

typedef float floatx4 __attribute__((ext_vector_type(4)));
typedef int   intx4   __attribute__((ext_vector_type(4)));
typedef int   intx8   __attribute__((ext_vector_type(8)));

__device__ __forceinline__ unsigned char f32_to_fp8(float v) {
    __hip_fp8_e4m3 t(v);
    return t.__x;
}

__device__ __forceinline__ float fp8_roundtrip(float v) {
    __hip_fp8_e4m3 t(v);
    return (float)t;
}

// async global->LDS, 16B per lane. LDS dest is wave-uniform base + lane*16.
__device__ __forceinline__ void async16(const void* g, void* l) {
    __builtin_amdgcn_global_load_lds((__attribute__((address_space(1))) void*)g,
                                     (__attribute__((address_space(3))) void*)l,
                                     16, 0, 0);
}

// ---- quantize + pack into MX-MFMA-fragment order (K-tile = 128) ----
// Layout: qX[rb][kt][subblock 2048B], rb = m>>4 (16-row blocks), kt = k>>7.
// Within a subblock: lane l16 (r = l16&15, g = l16>>4) owns k-window
// kt*128 + g*32 .. +31, stored as two 16B chunks:
//   bytes 0-15  at offset l16*16          (k window bytes 0-15)
//   bytes 16-31 at offset 1024 + l16*16   (k window bytes 16-31)
// GEMM reads each half as a lane-linear-16B ds_read_b128 (zero bank conflicts),
// and global_load_lds staging is an identity map. A and B share this map, so
// any hardware-internal k permutation cancels in the MFMA dot product.
__global__ void quant_pack_kernel(const float* __restrict__ in,
                                  unsigned char* __restrict__ out,
                                  const float* __restrict__ sp) {
    const int p = blockIdx.x * blockDim.x + threadIdx.x;  // one 16B packed chunk
    const float s = sp ? *sp : 1.0f;
    const int c7   = p & 127;            // chunk within subblock
    const int sb   = p >> 7;
    const int kt   = sb & (NKT - 1);
    const int rb   = sb >> 4;            // log2(NKT) = 4
    const int half = c7 >> 6;
    const int l16  = c7 & 63;
    const size_t m = (size_t)rb * 16 + (l16 & 15);
    const int   k0 = kt * 128 + (l16 >> 4) * 32 + half * 16;
    const float* src = in + m * K_DIM + k0;
    float f[16];
    *(float4*)(f)      = *(const float4*)(src);
    *(float4*)(f + 4)  = *(const float4*)(src + 4);
    *(float4*)(f + 8)  = *(const float4*)(src + 8);
    *(float4*)(f + 12) = *(const float4*)(src + 12);
    unsigned long long lo = 0, hi = 0;
#pragma unroll
    for (int j = 0; j < 8; ++j) {
        float v0 = fminf(fmaxf(f[j] * s, -0.5f), 0.5f);
        float v1 = fminf(fmaxf(f[j + 8] * s, -0.5f), 0.5f);
        lo |= (unsigned long long)f32_to_fp8(v0) << (8 * j);
        hi |= (unsigned long long)f32_to_fp8(v1) << (8 * j);
    }
    unsigned long long* dst = (unsigned long long*)(out + (size_t)p * 16);
    dst[0] = lo;
    dst[1] = hi;
}

// ---- MX-fp8 GEMM: 128x128 tile, BK=128, 4 waves (2x2), 16x16x128 scaled MFMA ----
// Scales fixed at e8m0 1.0 (0x7F) -> numerically identical to plain fp8 GEMM.
__global__ __launch_bounds__(256) void gemm_fp8_kernel(
        const unsigned char* __restrict__ qA, const unsigned char* __restrict__ qB,
        const float* __restrict__ bias, float* __restrict__ out) {
    __shared__ unsigned char Al[8 * 2048];   // 16 KB: 8 sub-blocks of 16 rows x 128 k
    __shared__ unsigned char Bl[8 * 2048];

    const int tid  = threadIdx.x;
    const int lane = tid & 63;
    const int wid  = tid >> 6;

    // XCD-aware swizzle: 4096 blocks % 8 == 0 -> bijective simple form
    const int cpx = gridDim.x >> 3;
    const int swz = (blockIdx.x & 7) * cpx + (blockIdx.x >> 3);
    const int bm = swz & 127;            // M/128 = 128 tiles
    const int bn = swz >> 7;             // N/128 = 32 tiles

    // staging: wave wid fills sub-blocks wid and wid+4 of each of Al, Bl
    const size_t a_rb0 = (size_t)bm * 8 + wid;
    const size_t b_rb0 = (size_t)bn * 8 + wid;
    const unsigned char* ga0 = qA + (a_rb0 << 15) + (lane << 4);  // rb stride = NKT*2048 = 1<<15
    const unsigned char* ga1 = ga0 + (4ull << 15);
    const unsigned char* gb0 = qB + (b_rb0 << 15) + (lane << 4);
    const unsigned char* gb1 = gb0 + (4ull << 15);
    unsigned char* la0 = Al + wid * 2048;            // wave-uniform dest
    unsigned char* la1 = Al + (4 + wid) * 2048;
    unsigned char* lb0 = Bl + wid * 2048;
    unsigned char* lb1 = Bl + (4 + wid) * 2048;

    // compute: wave (wid>>1, wid&1) owns a 64x64 output sub-tile
    const int sA = (wid >> 1) * 4;
    const int sB = (wid & 1) * 4;
    const int wr = (wid >> 1) * 64;
    const int wc = (wid & 1) * 64;
    const int fr = lane & 15;

    floatx4 acc[4][4] = {};

    for (int kt = 0; kt < NKT; ++kt) {
        const int ko = kt << 11;         // *2048
        async16(ga0 + ko, la0);  async16(ga0 + ko + 1024, la0 + 1024);
        async16(ga1 + ko, la1);  async16(ga1 + ko + 1024, la1 + 1024);
        async16(gb0 + ko, lb0);  async16(gb0 + ko + 1024, lb0 + 1024);
        async16(gb1 + ko, lb1);  async16(gb1 + ko + 1024, lb1 + 1024);
        __syncthreads();                 // compiler drains vmcnt before barrier

        intx8 afr[4], bfr[4];
#pragma unroll
        for (int i = 0; i < 4; ++i) {
            const unsigned char* base = Al + (sA + i) * 2048 + lane * 16;
            intx4 lo = *(const intx4*)(base);
            intx4 hi = *(const intx4*)(base + 1024);
            afr[i] = __builtin_shufflevector(lo, hi, 0, 1, 2, 3, 4, 5, 6, 7);
        }
#pragma unroll
        for (int i = 0; i < 4; ++i) {
            const unsigned char* base = Bl + (sB + i) * 2048 + lane * 16;
            intx4 lo = *(const intx4*)(base);
            intx4 hi = *(const intx4*)(base + 1024);
            bfr[i] = __builtin_shufflevector(lo, hi, 0, 1, 2, 3, 4, 5, 6, 7);
        }
#pragma unroll
        for (int mi = 0; mi < 4; ++mi)
#pragma unroll
            for (int ni = 0; ni < 4; ++ni)
                acc[mi][ni] = __builtin_amdgcn_mfma_scale_f32_16x16x128_f8f6f4(
                    afr[mi], bfr[ni], acc[mi][ni],
                    0, 0,                         // cbsz=fp8(e4m3), blgp=fp8(e4m3)
                    0, 0x7F7F7F7F,                // opsel_a, scale_a = 1.0 in every byte
                    0, 0x7F7F7F7F);               // opsel_b, scale_b = 1.0
        __syncthreads();                 // protect LDS before next stage
    }

    // epilogue: C/D layout col=lane&15, row=(lane>>4)*4+reg (shape-determined, m127/m128)
    const int orow0 = bm * 128 + wr + ((lane >> 4) << 2);
    const int ocol0 = bn * 128 + wc + fr;
#pragma unroll
    for (int ni = 0; ni < 4; ++ni) {
        const int oc = ocol0 + ni * 16;
        const float bv = bias[oc];
#pragma unroll
        for (int mi = 0; mi < 4; ++mi) {
#pragma unroll
            for (int j = 0; j < 4; ++j) {
                out[(size_t)(orow0 + mi * 16 + j) * N_DIM + oc] =
                    fp8_roundtrip(acc[mi][ni][j]) + bv;
            }
        }
    }
}

// ---- fallback (only if ws too small): 1 thread per output, exact fp32 accumulation ----
__global__ void naive_kernel(const float* __restrict__ x, const float* __restrict__ w,
                             const float* __restrict__ bias, const float* __restrict__ sp,
                             float* __restrict__ out) {
    const int ncol = blockIdx.x * blockDim.x + threadIdx.x;
    const int m = blockIdx.y;
    const float s = *sp;
    float acc = 0.f;
    for (int k = 0; k < K_DIM; ++k) {
        float q = fp8_roundtrip(fminf(fmaxf(x[(size_t)m * K_DIM + k] * s, -0.5f), 0.5f));
        acc += q * w[(size_t)ncol * K_DIM + k];
    }
    out[(size_t)m * N_DIM + ncol] = fp8_roundtrip(acc) + bias[ncol];
}

extern "C" void kernel_launch(void* const* d_in, const int* in_sizes, int n_in,
                              void* d_out, int out_size, void* d_ws, size_t ws_size,
                              hipStream_t stream) {
    const float* x     = (const float*)d_in[0];
    const float* w     = (const float*)d_in[1];
    const float* bias  = (const float*)d_in[2];
    const float* scale = (const float*)d_in[3];
    float* out = (float*)d_out;

    const size_t needA = (size_t)M_DIM * K_DIM;   // 33.5 MB fp8
    const size_t needB = (size_t)N_DIM * K_DIM;   //  8.4 MB fp8

    if (ws_size >= needA + needB) {
        unsigned char* qA = (unsigned char*)d_ws;
        unsigned char* qB = qA + needA;
        quant_pack_kernel<<<(M_DIM * K_DIM / 16) / 256, 256, 0, stream>>>(x, qA, scale);
        quant_pack_kernel<<<(N_DIM * K_DIM / 16) / 256, 256, 0, stream>>>(w, qB, nullptr);
        gemm_fp8_kernel<<<(M_DIM / 128) * (N_DIM / 128), 256, 0, stream>>>(qA, qB, bias, out);
    } else {
        dim3 g(N_DIM / 256, M_DIM);
        naive_kernel<<<g, 256, 0, stream>>>(x, w, bias, scale, out);
    }
}

// Round 4
// 243.050 us; speedup vs baseline: 2.5496x; 1.1151x over previous
//
#include <hip/hip_runtime.h>
#include <hip/hip_fp8.h>

#define M_DIM 16384
#define N_DIM 4096
#define K_DIM 2048
#define NKT   (K_DIM / 128)   // 16 K-tiles of 128
#define BM 256
#define BN 256

typedef float floatx4 __attribute__((ext_vector_type(4)));
typedef int   intx4   __attribute__((ext_vector_type(4)));
typedef int   intx8   __attribute__((ext_vector_type(8)));

__device__ __forceinline__ unsigned char f32_to_fp8(float v) {
    __hip_fp8_e4m3 t(v);
    return t.__x;
}

__device__ __forceinline__ float fp8_roundtrip(float v) {
    __hip_fp8_e4m3 t(v);
    return (float)t;
}

// async global->LDS, 16B per lane. LDS dest is wave-uniform base + lane*16.
__device__ __forceinline__ void async16(const void* g, void* l) {
    __builtin_amdgcn_global_load_lds((__attribute__((address_space(1))) void*)g,
                                     (__attribute__((address_space(3))) void*)l,
                                     16, 0, 0);
}

// read a lane-linear intx8 fragment: two 16B halves 1024B apart (zero-conflict)
__device__ __forceinline__ intx8 ld8(const unsigned char* p) {
    intx4 lo = *(const intx4*)(p);
    intx4 hi = *(const intx4*)(p + 1024);
    return __builtin_shufflevector(lo, hi, 0, 1, 2, 3, 4, 5, 6, 7);
}

// ---- quantize + pack into MX-MFMA-fragment order (K-tile = 128) ----
// Layout: qX[rb][kt][subblock 2048B], rb = m>>4 (16-row blocks), kt = k>>7.
// Within a subblock: lane l16 (r = l16&15, g = l16>>4) owns k-window
// kt*128 + g*32 .. +31: bytes 0-15 at offset l16*16, bytes 16-31 at 1024+l16*16.
// GEMM staging is identity (lane-linear 16B) and fragment reads are lane-linear
// ds_read_b128 -> zero bank conflicts. A and B share this map, so any
// hardware-internal k permutation cancels in the MFMA dot product.
__global__ void quant_pack_kernel(const float* __restrict__ in,
                                  unsigned char* __restrict__ out,
                                  const float* __restrict__ sp) {
    const int p = blockIdx.x * blockDim.x + threadIdx.x;  // one 16B packed chunk
    const float s = sp ? *sp : 1.0f;
    const int c7   = p & 127;            // chunk within subblock
    const int sb   = p >> 7;
    const int kt   = sb & (NKT - 1);
    const int rb   = sb >> 4;            // log2(NKT) = 4
    const int half = c7 >> 6;
    const int l16  = c7 & 63;
    const size_t m = (size_t)rb * 16 + (l16 & 15);
    const int   k0 = kt * 128 + (l16 >> 4) * 32 + half * 16;
    const float* src = in + m * K_DIM + k0;
    float f[16];
    *(float4*)(f)      = *(const float4*)(src);
    *(float4*)(f + 4)  = *(const float4*)(src + 4);
    *(float4*)(f + 8)  = *(const float4*)(src + 8);
    *(float4*)(f + 12) = *(const float4*)(src + 12);
    unsigned long long lo = 0, hi = 0;
#pragma unroll
    for (int j = 0; j < 8; ++j) {
        float v0 = fminf(fmaxf(f[j] * s, -0.5f), 0.5f);
        float v1 = fminf(fmaxf(f[j + 8] * s, -0.5f), 0.5f);
        lo |= (unsigned long long)f32_to_fp8(v0) << (8 * j);
        hi |= (unsigned long long)f32_to_fp8(v1) << (8 * j);
    }
    unsigned long long* dst = (unsigned long long*)(out + (size_t)p * 16);
    dst[0] = lo;
    dst[1] = hi;
}

// ---- MX-fp8 GEMM: 256x256 tile, BK=128, 8 waves (2Mx4N), 4-phase pipelined ----
// Scales fixed at e8m0 1.0 (0x7F) -> numerically identical to plain fp8 GEMM.
__global__ __launch_bounds__(512, 1) void gemm_fp8_kernel(
        const unsigned char* __restrict__ qA, const unsigned char* __restrict__ qB,
        const float* __restrict__ bias, float* __restrict__ out) {
    __shared__ unsigned char Al[2][16 * 2048];   // 2 x 32 KB (256 rows x 128 k)
    __shared__ unsigned char Bl[2][16 * 2048];   // 2 x 32 KB

    const int tid  = threadIdx.x;
    const int lane = tid & 63;
    const int wid  = tid >> 6;           // 0..7

    // XCD-aware swizzle: 1024 blocks % 8 == 0 -> bijective simple form
    const int cpx = gridDim.x >> 3;
    const int swz = (blockIdx.x & 7) * cpx + (blockIdx.x >> 3);
    const int bm = swz & 63;             // M/256 = 64 tiles
    const int bn = swz >> 6;             // N/256 = 16 tiles

    // staging: wave wid stages A sub-blocks {2wid, 2wid+1} and B likewise.
    // global sub-block stride = NKT*2048 = 32768 bytes.
    const unsigned char* gA = qA + ((size_t)(bm * 16 + 2 * wid) * NKT) * 2048 + (lane << 4);
    const unsigned char* gB = qB + ((size_t)(bn * 16 + 2 * wid) * NKT) * 2048 + (lane << 4);
    const int dst0 = (2 * wid) * 2048;   // wave-uniform LDS dest offsets
    const int dst1 = dst0 + 2048;

    // compute: wave (wid>>2, wid&3) owns a 128x64 output sub-tile
    const int sAb = (wid >> 2) * 8;      // A sub-block base (8 sub-blocks)
    const int sBb = (wid & 3) * 4;       // B sub-block base (4 sub-blocks)

    floatx4 acc[8][4] = {};

    // ---- prologue: stage tile 0 into buffer 0 ----
    async16(gA,         &Al[0][dst0]);         async16(gA + 1024,         &Al[0][dst0 + 1024]);
    async16(gA + 32768, &Al[0][dst1]);         async16(gA + 32768 + 1024, &Al[0][dst1 + 1024]);
    async16(gB,         &Bl[0][dst0]);         async16(gB + 1024,         &Bl[0][dst0 + 1024]);
    async16(gB + 32768, &Bl[0][dst1]);         async16(gB + 32768 + 1024, &Bl[0][dst1 + 1024]);
    __syncthreads();

    int cur = 0;
    for (int kt = 0; kt < NKT; ++kt) {
        const int konext = ((kt + 1) & (NKT - 1)) << 11;   // *2048
        const int nb = cur ^ 1;
        const bool more = (kt + 1 < NKT);
        intx8 bfr[4];

#pragma unroll
        for (int p = 0; p < 4; ++p) {
            // ds-reads for this phase (from stable buffer cur)
            const unsigned char* Abase = &Al[cur][(sAb + 2 * p) * 2048 + (lane << 4)];
            intx8 a0 = ld8(Abase);
            intx8 a1 = ld8(Abase + 2048);
            if (p == 0) {
#pragma unroll
                for (int ni = 0; ni < 4; ++ni)
                    bfr[ni] = ld8(&Bl[cur][(sBb + ni) * 2048 + (lane << 4)]);
                if (more) {   // front-loaded staging: A in phase 0
                    async16(gA + konext,                &Al[nb][dst0]);
                    async16(gA + konext + 1024,         &Al[nb][dst0 + 1024]);
                    async16(gA + konext + 32768,        &Al[nb][dst1]);
                    async16(gA + konext + 32768 + 1024, &Al[nb][dst1 + 1024]);
                }
            } else if (p == 1) {
                if (more) {   // B in phase 1 -> last load issued ~3 phases before drain
                    async16(gB + konext,                &Bl[nb][dst0]);
                    async16(gB + konext + 1024,         &Bl[nb][dst0 + 1024]);
                    async16(gB + konext + 32768,        &Bl[nb][dst1]);
                    async16(gB + konext + 32768 + 1024, &Bl[nb][dst1 + 1024]);
                }
            }
            __builtin_amdgcn_s_barrier();
            asm volatile("s_waitcnt lgkmcnt(0)" ::: "memory");
            __builtin_amdgcn_sched_barrier(0);
            __builtin_amdgcn_s_setprio(1);
#pragma unroll
            for (int ni = 0; ni < 4; ++ni) {
                acc[2 * p][ni] = __builtin_amdgcn_mfma_scale_f32_16x16x128_f8f6f4(
                    a0, bfr[ni], acc[2 * p][ni], 0, 0, 0, 0x7F7F7F7F, 0, 0x7F7F7F7F);
                acc[2 * p + 1][ni] = __builtin_amdgcn_mfma_scale_f32_16x16x128_f8f6f4(
                    a1, bfr[ni], acc[2 * p + 1][ni], 0, 0, 0, 0x7F7F7F7F, 0, 0x7F7F7F7F);
            }
            __builtin_amdgcn_s_setprio(0);
            if (p < 3) __builtin_amdgcn_s_barrier();
        }
        // tile boundary: drain staging queue (vmcnt) + full barrier before
        // anyone reads buffer nb or overwrites buffer cur
        __syncthreads();
        cur ^= 1;
    }

    // epilogue: C/D layout col=lane&15, row=(lane>>4)*4+reg (shape-determined)
    const int orow0 = bm * 256 + (wid >> 2) * 128 + ((lane >> 4) << 2);
    const int ocol0 = bn * 256 + (wid & 3) * 64 + (lane & 15);
#pragma unroll
    for (int ni = 0; ni < 4; ++ni) {
        const int oc = ocol0 + ni * 16;
        const float bv = bias[oc];
#pragma unroll
        for (int mi = 0; mi < 8; ++mi) {
#pragma unroll
            for (int j = 0; j < 4; ++j) {
                out[(size_t)(orow0 + mi * 16 + j) * N_DIM + oc] =
                    fp8_roundtrip(acc[mi][ni][j]) + bv;
            }
        }
    }
}

// ---- fallback (only if ws too small): 1 thread per output, exact fp32 accumulation ----
__global__ void naive_kernel(const float* __restrict__ x, const float* __restrict__ w,
                             const float* __restrict__ bias, const float* __restrict__ sp,
                             float* __restrict__ out) {
    const int ncol = blockIdx.x * blockDim.x + threadIdx.x;
    const int m = blockIdx.y;
    const float s = *sp;
    float acc = 0.f;
    for (int k = 0; k < K_DIM; ++k) {
        float q = fp8_roundtrip(fminf(fmaxf(x[(size_t)m * K_DIM + k] * s, -0.5f), 0.5f));
        acc += q * w[(size_t)ncol * K_DIM + k];
    }
    out[(size_t)m * N_DIM + ncol] = fp8_roundtrip(acc) + bias[ncol];
}

extern "C" void kernel_launch(void* const* d_in, const int* in_sizes, int n_in,
                              void* d_out, int out_size, void* d_ws, size_t ws_size,
                              hipStream_t stream) {
    const float* x     = (const float*)d_in[0];
    const float* w     = (const float*)d_in[1];
    const float* bias  = (const float*)d_in[2];
    const float* scale = (const float*)d_in[3];
    float* out = (float*)d_out;

    const size_t needA = (size_t)M_DIM * K_DIM;   // 33.5 MB fp8
    const size_t needB = (size_t)N_DIM * K_DIM;   //  8.4 MB fp8

    if (ws_size >= needA + needB) {
        unsigned char* qA = (unsigned char*)d_ws;
        unsigned char* qB = qA + needA;
        quant_pack_kernel<<<(M_DIM * K_DIM / 16) / 256, 256, 0, stream>>>(x, qA, scale);
        quant_pack_kernel<<<(N_DIM * K_DIM / 16) / 256, 256, 0, stream>>>(w, qB, nullptr);
        gemm_fp8_kernel<<<(M_DIM / BM) * (N_DIM / BN), 512, 0, stream>>>(qA, qB, bias, out);
    } else {
        dim3 g(N_DIM / 256, M_DIM);
        naive_kernel<<<g, 256, 0, stream>>>(x, w, bias, scale, out);
    }
}

// Round 5
// 210.064 us; speedup vs baseline: 2.9499x; 1.1570x over previous
//
#include <hip/hip_runtime.h>
#include <hip/hip_fp8.h>

#define M_DIM 16384
#define N_DIM 4096
#define K_DIM 2048
#define NT    (K_DIM / 128)    // 16 staged K-tiles (BK=128)
#define NSB   (K_DIM / 64)     // 32 k-sub-blocks per 32-row block (32 rows x 64 k each)

typedef float floatx16 __attribute__((ext_vector_type(16)));
typedef int   intx4    __attribute__((ext_vector_type(4)));
typedef int   intx8    __attribute__((ext_vector_type(8)));

__device__ __forceinline__ unsigned char f32_to_fp8(float v) {
    __hip_fp8_e4m3 t(v);
    return t.__x;
}

__device__ __forceinline__ float fp8_roundtrip(float v) {
    __hip_fp8_e4m3 t(v);
    return (float)t;
}

// async global->LDS, 16B per lane. LDS dest is wave-uniform base + lane*16.
__device__ __forceinline__ void async16(const void* g, void* l) {
    __builtin_amdgcn_global_load_lds((__attribute__((address_space(1))) void*)g,
                                     (__attribute__((address_space(3))) void*)l,
                                     16, 0, 0);
}

// read a lane-linear 32B fragment: two 16B halves 1024B apart (zero-conflict)
__device__ __forceinline__ intx8 ld8(const unsigned char* p) {
    intx4 lo = *(const intx4*)(p);
    intx4 hi = *(const intx4*)(p + 1024);
    return __builtin_shufflevector(lo, hi, 0, 1, 2, 3, 4, 5, 6, 7);
}

// ---- quantize + pack into 32x32x64-MFMA fragment order ----
// Sub-block = 32 rows x 64 k = 2048 B. qX[rb][kt][2048], rb = m>>5, kt = k>>6.
// Within a sub-block: lane l (r = l&31, h = l>>5) owns k-window kt*64 + h*32 .. +31,
// stored as bytes 0-15 at l*16 and bytes 16-31 at 1024 + l*16.
// GEMM staging is identity (lane-linear 16B) and fragment reads are lane-linear
// ds_read_b128 -> zero bank conflicts. A and B share this map, so any
// hardware-internal k permutation cancels in the MFMA dot product.
__global__ void quant_pack_kernel(const float* __restrict__ in,
                                  unsigned char* __restrict__ out,
                                  const float* __restrict__ sp) {
    const int p = blockIdx.x * blockDim.x + threadIdx.x;  // one 16B packed chunk
    const float s = sp ? *sp : 1.0f;
    const int c    = p & 127;            // chunk within sub-block
    const int sb   = p >> 7;
    const int kt   = sb & (NSB - 1);
    const int rb   = sb >> 5;            // log2(NSB) = 5
    const int half = c >> 6;
    const int l    = c & 63;
    const size_t m = (size_t)rb * 32 + (l & 31);
    const int   k0 = kt * 64 + (l >> 5) * 32 + half * 16;
    const float* src = in + m * K_DIM + k0;
    float f[16];
    *(float4*)(f)      = *(const float4*)(src);
    *(float4*)(f + 4)  = *(const float4*)(src + 4);
    *(float4*)(f + 8)  = *(const float4*)(src + 8);
    *(float4*)(f + 12) = *(const float4*)(src + 12);
    unsigned long long lo = 0, hi = 0;
#pragma unroll
    for (int j = 0; j < 8; ++j) {
        float v0 = fminf(fmaxf(f[j] * s, -0.5f), 0.5f);
        float v1 = fminf(fmaxf(f[j + 8] * s, -0.5f), 0.5f);
        lo |= (unsigned long long)f32_to_fp8(v0) << (8 * j);
        hi |= (unsigned long long)f32_to_fp8(v1) << (8 * j);
    }
    unsigned long long* dst = (unsigned long long*)(out + (size_t)p * 16);
    dst[0] = lo;
    dst[1] = hi;
}

// ---- MX-fp8 GEMM: 256x256 tile, BK=128, 8 waves (2Mx4N), 32x32x64 scaled MFMA ----
// 2 balanced phases per K-tile (one per K=64 step): 12 ds_read_b128 + 8 MFMA each.
// Scales fixed at e8m0 1.0 (0x7F) -> numerically identical to plain fp8 GEMM.
__global__ __launch_bounds__(512, 1) void gemm_fp8_kernel(
        const unsigned char* __restrict__ qA, const unsigned char* __restrict__ qB,
        const float* __restrict__ bias, float* __restrict__ out) {
    __shared__ unsigned char Al[2][16 * 2048];   // 2 x 32 KB: 16 sub-blocks (8 rb x 2 ks)
    __shared__ unsigned char Bl[2][16 * 2048];

    const int tid  = threadIdx.x;
    const int lane = tid & 63;
    const int wid  = tid >> 6;           // 0..7

    // XCD-aware swizzle: 1024 blocks % 8 == 0 -> bijective simple form
    const int cpx = gridDim.x >> 3;
    const int swz = (blockIdx.x & 7) * cpx + (blockIdx.x >> 3);
    const int bm = swz & 63;             // M/256 = 64 tiles
    const int bn = swz >> 6;             // N/256 = 16 tiles

    // staging: wave wid owns row-block (bm*8+wid); per tile its 2 k-sub-blocks are a
    // contiguous 4 KB run in global (strip stride 64 KB) and in LDS (wid*4096).
    const unsigned char* gAw = qA + ((size_t)(bm * 8 + wid) << 16) + (lane << 4);
    const unsigned char* gBw = qB + ((size_t)(bn * 8 + wid) << 16) + (lane << 4);

    // compute: wave (g = wid>>2, c = wid&3) owns a 128x64 output sub-tile
    const int g  = wid >> 2;
    const int cc = wid & 3;

    floatx16 acc[4][2] = {};             // 4 row-blocks x 2 col-blocks of 32x32

    // ---- prologue: stage tile 0 into buffer 0 ----
#pragma unroll
    for (int j = 0; j < 4; ++j) async16(gAw + j * 1024, &Al[0][wid * 4096 + j * 1024]);
#pragma unroll
    for (int j = 0; j < 4; ++j) async16(gBw + j * 1024, &Bl[0][wid * 4096 + j * 1024]);
    __syncthreads();

    int cur = 0;
    for (int t = 0; t < NT; ++t) {
        const int nb = cur ^ 1;
        const bool more = (t + 1 < NT);
        const size_t goff = (size_t)(t + 1) * 4096;
#pragma unroll
        for (int ks = 0; ks < 2; ++ks) {
            intx8 a[4], b[2];
#pragma unroll
            for (int mi = 0; mi < 4; ++mi)
                a[mi] = ld8(&Al[cur][((4 * g + mi) * 2 + ks) * 2048 + (lane << 4)]);
#pragma unroll
            for (int ni = 0; ni < 2; ++ni)
                b[ni] = ld8(&Bl[cur][((2 * cc + ni) * 2 + ks) * 2048 + (lane << 4)]);
            if (ks == 0 && more) {       // stage next tile; full phase of cover pre-drain
#pragma unroll
                for (int j = 0; j < 4; ++j)
                    async16(gAw + goff + j * 1024, &Al[nb][wid * 4096 + j * 1024]);
#pragma unroll
                for (int j = 0; j < 4; ++j)
                    async16(gBw + goff + j * 1024, &Bl[nb][wid * 4096 + j * 1024]);
            }
            __builtin_amdgcn_s_barrier();
            asm volatile("s_waitcnt lgkmcnt(0)" ::: "memory");
            __builtin_amdgcn_sched_barrier(0);
            __builtin_amdgcn_s_setprio(1);
#pragma unroll
            for (int mi = 0; mi < 4; ++mi)
#pragma unroll
                for (int ni = 0; ni < 2; ++ni)
                    acc[mi][ni] = __builtin_amdgcn_mfma_scale_f32_32x32x64_f8f6f4(
                        a[mi], b[ni], acc[mi][ni], 0, 0, 0, 0x7F7F7F7F, 0, 0x7F7F7F7F);
            __builtin_amdgcn_s_setprio(0);
            if (ks == 0) __builtin_amdgcn_s_barrier();
        }
        // tile boundary: drain staging queue + full barrier (2-buffer correctness)
        __syncthreads();
        cur = nb;
    }

    // epilogue: 32x32 C/D layout col=lane&31, row=(r&3)+8*(r>>2)+4*(lane>>5)
    const int orow_b = bm * 256 + g * 128 + ((lane >> 5) << 2);
    const int ocol_b = bn * 256 + cc * 64 + (lane & 31);
#pragma unroll
    for (int ni = 0; ni < 2; ++ni) {
        const int oc = ocol_b + ni * 32;
        const float bv = bias[oc];
#pragma unroll
        for (int mi = 0; mi < 4; ++mi) {
#pragma unroll
            for (int r = 0; r < 16; ++r) {
                const int orow = orow_b + mi * 32 + (r & 3) + 8 * (r >> 2);
                out[(size_t)orow * N_DIM + oc] = fp8_roundtrip(acc[mi][ni][r]) + bv;
            }
        }
    }
}

// ---- fallback (only if ws too small): 1 thread per output, exact fp32 accumulation ----
__global__ void naive_kernel(const float* __restrict__ x, const float* __restrict__ w,
                             const float* __restrict__ bias, const float* __restrict__ sp,
                             float* __restrict__ out) {
    const int ncol = blockIdx.x * blockDim.x + threadIdx.x;
    const int m = blockIdx.y;
    const float s = *sp;
    float acc = 0.f;
    for (int k = 0; k < K_DIM; ++k) {
        float q = fp8_roundtrip(fminf(fmaxf(x[(size_t)m * K_DIM + k] * s, -0.5f), 0.5f));
        acc += q * w[(size_t)ncol * K_DIM + k];
    }
    out[(size_t)m * N_DIM + ncol] = fp8_roundtrip(acc) + bias[ncol];
}

extern "C" void kernel_launch(void* const* d_in, const int* in_sizes, int n_in,
                              void* d_out, int out_size, void* d_ws, size_t ws_size,
                              hipStream_t stream) {
    const float* x     = (const float*)d_in[0];
    const float* w     = (const float*)d_in[1];
    const float* bias  = (const float*)d_in[2];
    const float* scale = (const float*)d_in[3];
    float* out = (float*)d_out;

    const size_t needA = (size_t)M_DIM * K_DIM;   // 33.5 MB fp8
    const size_t needB = (size_t)N_DIM * K_DIM;   //  8.4 MB fp8

    if (ws_size >= needA + needB) {
        unsigned char* qA = (unsigned char*)d_ws;
        unsigned char* qB = qA + needA;
        quant_pack_kernel<<<(M_DIM * K_DIM / 16) / 256, 256, 0, stream>>>(x, qA, scale);
        quant_pack_kernel<<<(N_DIM * K_DIM / 16) / 256, 256, 0, stream>>>(w, qB, nullptr);
        gemm_fp8_kernel<<<(M_DIM / 256) * (N_DIM / 256), 512, 0, stream>>>(qA, qB, bias, out);
    } else {
        dim3 g(N_DIM / 256, M_DIM);
        naive_kernel<<<g, 256, 0, stream>>>(x, w, bias, scale, out);
    }
}

// Round 6
// 209.776 us; speedup vs baseline: 2.9540x; 1.0014x over previous
//
#include <hip/hip_runtime.h>
#include <hip/hip_fp8.h>

#define M_DIM 16384
#define N_DIM 4096
#define K_DIM 2048
#define NT    (K_DIM / 128)    // 16 staged K-tiles (BK=128)
#define NSB   (K_DIM / 64)     // 32 k-sub-blocks per 32-row block (32 rows x 64 k each)

typedef float floatx16 __attribute__((ext_vector_type(16)));
typedef int   intx4    __attribute__((ext_vector_type(4)));
typedef int   intx8    __attribute__((ext_vector_type(8)));

__device__ __forceinline__ unsigned char f32_to_fp8(float v) {
    __hip_fp8_e4m3 t(v);
    return t.__x;
}

__device__ __forceinline__ float fp8_roundtrip(float v) {
    __hip_fp8_e4m3 t(v);
    return (float)t;
}

// async global->LDS, 16B per lane. LDS dest is wave-uniform base + lane*16.
__device__ __forceinline__ void async16(const void* g, void* l) {
    __builtin_amdgcn_global_load_lds((__attribute__((address_space(1))) void*)g,
                                     (__attribute__((address_space(3))) void*)l,
                                     16, 0, 0);
}

// read a lane-linear 32B fragment: two 16B halves 1024B apart (zero-conflict)
__device__ __forceinline__ intx8 ld8(const unsigned char* p) {
    intx4 lo = *(const intx4*)(p);
    intx4 hi = *(const intx4*)(p + 1024);
    return __builtin_shufflevector(lo, hi, 0, 1, 2, 3, 4, 5, 6, 7);
}

// ---- quantize + pack into 32x32x64-MFMA fragment order ----
// Sub-block = 32 rows x 64 k = 2048 B. qX[rb][kt][2048], rb = m>>5, kt = k>>6.
// Within a sub-block: lane l (r = l&31, h = l>>5) owns k-window kt*64 + h*32 .. +31,
// stored as bytes 0-15 at l*16 and bytes 16-31 at 1024 + l*16.
// GEMM staging is identity (lane-linear 16B) and fragment reads are lane-linear
// ds_read_b128 -> zero bank conflicts. A and B share this map, so any
// hardware-internal k permutation cancels in the MFMA dot product.
__global__ void quant_pack_kernel(const float* __restrict__ in,
                                  unsigned char* __restrict__ out,
                                  const float* __restrict__ sp) {
    const int p = blockIdx.x * blockDim.x + threadIdx.x;  // one 16B packed chunk
    const float s = sp ? *sp : 1.0f;
    const int c    = p & 127;            // chunk within sub-block
    const int sb   = p >> 7;
    const int kt   = sb & (NSB - 1);
    const int rb   = sb >> 5;            // log2(NSB) = 5
    const int half = c >> 6;
    const int l    = c & 63;
    const size_t m = (size_t)rb * 32 + (l & 31);
    const int   k0 = kt * 64 + (l >> 5) * 32 + half * 16;
    const float* src = in + m * K_DIM + k0;
    float f[16];
    *(float4*)(f)      = *(const float4*)(src);
    *(float4*)(f + 4)  = *(const float4*)(src + 4);
    *(float4*)(f + 8)  = *(const float4*)(src + 8);
    *(float4*)(f + 12) = *(const float4*)(src + 12);
    unsigned long long lo = 0, hi = 0;
#pragma unroll
    for (int j = 0; j < 8; ++j) {
        float v0 = fminf(fmaxf(f[j] * s, -0.5f), 0.5f);
        float v1 = fminf(fmaxf(f[j + 8] * s, -0.5f), 0.5f);
        lo |= (unsigned long long)f32_to_fp8(v0) << (8 * j);
        hi |= (unsigned long long)f32_to_fp8(v1) << (8 * j);
    }
    unsigned long long* dst = (unsigned long long*)(out + (size_t)p * 16);
    dst[0] = lo;
    dst[1] = hi;
}

// ---- MX-fp8 GEMM: 256x256 tile, BK=128, 8 waves (2Mx4N), 32x32x64 scaled MFMA ----
// One barrier per K-tile; NO intra-tile barriers or manual waitcnts: plain-C
// ds_reads let the compiler emit counted lgkmcnt so LDS service overlaps MFMA,
// and waves slip within the tile so pipes overlap across waves.
// Scales fixed at e8m0 1.0 (0x7F) -> numerically identical to plain fp8 GEMM.
__global__ __launch_bounds__(512, 1) void gemm_fp8_kernel(
        const unsigned char* __restrict__ qA, const unsigned char* __restrict__ qB,
        const float* __restrict__ bias, float* __restrict__ out) {
    __shared__ unsigned char Al[2][16 * 2048];   // 2 x 32 KB: 16 sub-blocks (8 rb x 2 ks)
    __shared__ unsigned char Bl[2][16 * 2048];

    const int tid  = threadIdx.x;
    const int lane = tid & 63;
    const int wid  = tid >> 6;           // 0..7

    // XCD-aware swizzle: 1024 blocks % 8 == 0 -> bijective simple form
    const int cpx = gridDim.x >> 3;
    const int swz = (blockIdx.x & 7) * cpx + (blockIdx.x >> 3);
    const int bm = swz & 63;             // M/256 = 64 tiles
    const int bn = swz >> 6;             // N/256 = 16 tiles

    // staging: wave wid owns row-block (bm*8+wid); per tile its 2 k-sub-blocks are a
    // contiguous 4 KB run in global (strip stride 64 KB) and in LDS (wid*4096).
    const unsigned char* gAw = qA + ((size_t)(bm * 8 + wid) << 16) + (lane << 4);
    const unsigned char* gBw = qB + ((size_t)(bn * 8 + wid) << 16) + (lane << 4);

    // compute: wave (g = wid>>2, c = wid&3) owns a 128x64 output sub-tile
    const int g  = wid >> 2;
    const int cc = wid & 3;

    floatx16 acc[4][2] = {};             // 4 row-blocks x 2 col-blocks of 32x32

    // ---- prologue: stage tile 0 into buffer 0 ----
#pragma unroll
    for (int j = 0; j < 4; ++j) async16(gAw + j * 1024, &Al[0][wid * 4096 + j * 1024]);
#pragma unroll
    for (int j = 0; j < 4; ++j) async16(gBw + j * 1024, &Bl[0][wid * 4096 + j * 1024]);
    __syncthreads();

    int cur = 0;
    for (int t = 0; t < NT; ++t) {
        const int nb = cur ^ 1;
        const bool more = (t + 1 < NT);
        const size_t goff = (size_t)(t + 1) * 4096;
#pragma unroll
        for (int ks = 0; ks < 2; ++ks) {
            intx8 a[4], b[2];
#pragma unroll
            for (int mi = 0; mi < 4; ++mi)
                a[mi] = ld8(&Al[cur][((4 * g + mi) * 2 + ks) * 2048 + (lane << 4)]);
#pragma unroll
            for (int ni = 0; ni < 2; ++ni)
                b[ni] = ld8(&Bl[cur][((2 * cc + ni) * 2 + ks) * 2048 + (lane << 4)]);
            if (ks == 0 && more) {       // stage next tile into the other buffer
#pragma unroll
                for (int j = 0; j < 4; ++j)
                    async16(gAw + goff + j * 1024, &Al[nb][wid * 4096 + j * 1024]);
#pragma unroll
                for (int j = 0; j < 4; ++j)
                    async16(gBw + goff + j * 1024, &Bl[nb][wid * 4096 + j * 1024]);
            }
            __builtin_amdgcn_s_setprio(1);
#pragma unroll
            for (int mi = 0; mi < 4; ++mi)
#pragma unroll
                for (int ni = 0; ni < 2; ++ni)
                    acc[mi][ni] = __builtin_amdgcn_mfma_scale_f32_32x32x64_f8f6f4(
                        a[mi], b[ni], acc[mi][ni], 0, 0, 0, 0x7F7F7F7F, 0, 0x7F7F7F7F);
            __builtin_amdgcn_s_setprio(0);
        }
        // tile boundary: drain staging queue (vmcnt) + sync double buffers.
        // Staging was issued ~one full MFMA cluster (~2000+ cyc) before this
        // drain -> HBM/L2 latency covered.
        __syncthreads();
        cur = nb;
    }

    // epilogue: 32x32 C/D layout col=lane&31, row=(r&3)+8*(r>>2)+4*(lane>>5)
    const int orow_b = bm * 256 + g * 128 + ((lane >> 5) << 2);
    const int ocol_b = bn * 256 + cc * 64 + (lane & 31);
#pragma unroll
    for (int ni = 0; ni < 2; ++ni) {
        const int oc = ocol_b + ni * 32;
        const float bv = bias[oc];
#pragma unroll
        for (int mi = 0; mi < 4; ++mi) {
#pragma unroll
            for (int r = 0; r < 16; ++r) {
                const int orow = orow_b + mi * 32 + (r & 3) + 8 * (r >> 2);
                out[(size_t)orow * N_DIM + oc] = fp8_roundtrip(acc[mi][ni][r]) + bv;
            }
        }
    }
}

// ---- fallback (only if ws too small): 1 thread per output, exact fp32 accumulation ----
__global__ void naive_kernel(const float* __restrict__ x, const float* __restrict__ w,
                             const float* __restrict__ bias, const float* __restrict__ sp,
                             float* __restrict__ out) {
    const int ncol = blockIdx.x * blockDim.x + threadIdx.x;
    const int m = blockIdx.y;
    const float s = *sp;
    float acc = 0.f;
    for (int k = 0; k < K_DIM; ++k) {
        float q = fp8_roundtrip(fminf(fmaxf(x[(size_t)m * K_DIM + k] * s, -0.5f), 0.5f));
        acc += q * w[(size_t)ncol * K_DIM + k];
    }
    out[(size_t)m * N_DIM + ncol] = fp8_roundtrip(acc) + bias[ncol];
}

extern "C" void kernel_launch(void* const* d_in, const int* in_sizes, int n_in,
                              void* d_out, int out_size, void* d_ws, size_t ws_size,
                              hipStream_t stream) {
    const float* x     = (const float*)d_in[0];
    const float* w     = (const float*)d_in[1];
    const float* bias  = (const float*)d_in[2];
    const float* scale = (const float*)d_in[3];
    float* out = (float*)d_out;

    const size_t needA = (size_t)M_DIM * K_DIM;   // 33.5 MB fp8
    const size_t needB = (size_t)N_DIM * K_DIM;   //  8.4 MB fp8

    if (ws_size >= needA + needB) {
        unsigned char* qA = (unsigned char*)d_ws;
        unsigned char* qB = qA + needA;
        quant_pack_kernel<<<(M_DIM * K_DIM / 16) / 256, 256, 0, stream>>>(x, qA, scale);
        quant_pack_kernel<<<(N_DIM * K_DIM / 16) / 256, 256, 0, stream>>>(w, qB, nullptr);
        gemm_fp8_kernel<<<(M_DIM / 256) * (N_DIM / 256), 512, 0, stream>>>(qA, qB, bias, out);
    } else {
        dim3 g(N_DIM / 256, M_DIM);
        naive_kernel<<<g, 256, 0, stream>>>(x, w, bias, scale, out);
    }
}

// Round 7
// 209.274 us; speedup vs baseline: 2.9611x; 1.0024x over previous
//
#include <hip/hip_runtime.h>
#include <hip/hip_fp8.h>

#define M_DIM 16384
#define N_DIM 4096
#define K_DIM 2048
#define NT    (K_DIM / 128)    // 16 staged K-tiles (BK=128)
#define NSB   (K_DIM / 64)     // 32 k-sub-blocks per 32-row block (32 rows x 64 k each)

typedef float floatx16 __attribute__((ext_vector_type(16)));
typedef int   intx4    __attribute__((ext_vector_type(4)));
typedef int   intx8    __attribute__((ext_vector_type(8)));

__device__ __forceinline__ unsigned char f32_to_fp8(float v) {
    __hip_fp8_e4m3 t(v);
    return t.__x;
}

__device__ __forceinline__ float fp8_roundtrip(float v) {
    __hip_fp8_e4m3 t(v);
    return (float)t;
}

// async global->LDS, 16B per lane. LDS dest is wave-uniform base + lane*16.
__device__ __forceinline__ void async16(const void* g, void* l) {
    __builtin_amdgcn_global_load_lds((__attribute__((address_space(1))) void*)g,
                                     (__attribute__((address_space(3))) void*)l,
                                     16, 0, 0);
}

// read a lane-linear 32B fragment: two 16B halves 1024B apart (zero-conflict)
__device__ __forceinline__ intx8 ld8(const unsigned char* p) {
    intx4 lo = *(const intx4*)(p);
    intx4 hi = *(const intx4*)(p + 1024);
    return __builtin_shufflevector(lo, hi, 0, 1, 2, 3, 4, 5, 6, 7);
}

// ---- quantize + pack into 32x32x64-MFMA fragment order ----
// Sub-block = 32 rows x 64 k = 2048 B. qX[rb][kt][2048], rb = m>>5, kt = k>>6.
// Within a sub-block: lane l (r = l&31, h = l>>5) owns k-window kt*64 + h*32 .. +31,
// stored as bytes 0-15 at l*16 and bytes 16-31 at 1024 + l*16.
// GEMM staging is identity (lane-linear 16B) and fragment reads are lane-linear
// ds_read_b128 -> zero bank conflicts. A and B share this map, so any
// hardware-internal k permutation cancels in the MFMA dot product.
__global__ void quant_pack_kernel(const float* __restrict__ in,
                                  unsigned char* __restrict__ out,
                                  const float* __restrict__ sp) {
    const int p = blockIdx.x * blockDim.x + threadIdx.x;  // one 16B packed chunk
    const float s = sp ? *sp : 1.0f;
    const int c    = p & 127;            // chunk within sub-block
    const int sb   = p >> 7;
    const int kt   = sb & (NSB - 1);
    const int rb   = sb >> 5;            // log2(NSB) = 5
    const int half = c >> 6;
    const int l    = c & 63;
    const size_t m = (size_t)rb * 32 + (l & 31);
    const int   k0 = kt * 64 + (l >> 5) * 32 + half * 16;
    const float* src = in + m * K_DIM + k0;
    float f[16];
    *(float4*)(f)      = *(const float4*)(src);
    *(float4*)(f + 4)  = *(const float4*)(src + 4);
    *(float4*)(f + 8)  = *(const float4*)(src + 8);
    *(float4*)(f + 12) = *(const float4*)(src + 12);
    unsigned long long lo = 0, hi = 0;
#pragma unroll
    for (int j = 0; j < 8; ++j) {
        float v0 = fminf(fmaxf(f[j] * s, -0.5f), 0.5f);
        float v1 = fminf(fmaxf(f[j + 8] * s, -0.5f), 0.5f);
        lo |= (unsigned long long)f32_to_fp8(v0) << (8 * j);
        hi |= (unsigned long long)f32_to_fp8(v1) << (8 * j);
    }
    unsigned long long* dst = (unsigned long long*)(out + (size_t)p * 16);
    dst[0] = lo;
    dst[1] = hi;
}

// ---- MX-fp8 GEMM: 256x256 tile, BK=128, 8 waves (2Mx4N), 32x32x64 scaled MFMA ----
// Fragment-level register double-buffering: ks1's ds_reads are issued BEFORE
// ks0's MFMA cluster into a distinct register set, so the LDS pipe services
// ks1 under ks0's MFMA execution (counted lgkmcnt; no WAW interlock).
// Scales fixed at e8m0 1.0 (0x7F) -> numerically identical to plain fp8 GEMM.
__global__ __launch_bounds__(512, 1) void gemm_fp8_kernel(
        const unsigned char* __restrict__ qA, const unsigned char* __restrict__ qB,
        const float* __restrict__ bias, float* __restrict__ out) {
    __shared__ unsigned char Al[2][16 * 2048];   // 2 x 32 KB: 16 sub-blocks (8 rb x 2 ks)
    __shared__ unsigned char Bl[2][16 * 2048];

    const int tid  = threadIdx.x;
    const int lane = tid & 63;
    const int wid  = tid >> 6;           // 0..7

    // XCD-aware swizzle: 1024 blocks % 8 == 0 -> bijective simple form
    const int cpx = gridDim.x >> 3;
    const int swz = (blockIdx.x & 7) * cpx + (blockIdx.x >> 3);
    const int bm = swz & 63;             // M/256 = 64 tiles
    const int bn = swz >> 6;             // N/256 = 16 tiles

    // staging: wave wid owns row-block (bm*8+wid); per tile its 2 k-sub-blocks are a
    // contiguous 4 KB run in global (strip stride 64 KB) and in LDS (wid*4096).
    const unsigned char* gAw = qA + ((size_t)(bm * 8 + wid) << 16) + (lane << 4);
    const unsigned char* gBw = qB + ((size_t)(bn * 8 + wid) << 16) + (lane << 4);

    // compute: wave (g = wid>>2, c = wid&3) owns a 128x64 output sub-tile
    const int g  = wid >> 2;
    const int cc = wid & 3;

    floatx16 acc[4][2] = {};             // 4 row-blocks x 2 col-blocks of 32x32

    // ---- prologue: stage tile 0 into buffer 0 ----
#pragma unroll
    for (int j = 0; j < 4; ++j) async16(gAw + j * 1024, &Al[0][wid * 4096 + j * 1024]);
#pragma unroll
    for (int j = 0; j < 4; ++j) async16(gBw + j * 1024, &Bl[0][wid * 4096 + j * 1024]);
    __syncthreads();

    int cur = 0;
    for (int t = 0; t < NT; ++t) {
        const int nb = cur ^ 1;
        const bool more = (t + 1 < NT);
        const size_t goff = (size_t)(t + 1) * 4096;

        intx8 a0[4], b0[2], a1[4], b1[2];
        // ks0 fragment reads
#pragma unroll
        for (int mi = 0; mi < 4; ++mi)
            a0[mi] = ld8(&Al[cur][((4 * g + mi) * 2 + 0) * 2048 + (lane << 4)]);
#pragma unroll
        for (int ni = 0; ni < 2; ++ni)
            b0[ni] = ld8(&Bl[cur][((2 * cc + ni) * 2 + 0) * 2048 + (lane << 4)]);
        // stage next tile into the other buffer (vmem queue; drained at syncthreads)
        if (more) {
#pragma unroll
            for (int j = 0; j < 4; ++j)
                async16(gAw + goff + j * 1024, &Al[nb][wid * 4096 + j * 1024]);
#pragma unroll
            for (int j = 0; j < 4; ++j)
                async16(gBw + goff + j * 1024, &Bl[nb][wid * 4096 + j * 1024]);
        }
        // ks1 fragment reads — distinct registers, issued BEFORE ks0 MFMAs
#pragma unroll
        for (int mi = 0; mi < 4; ++mi)
            a1[mi] = ld8(&Al[cur][((4 * g + mi) * 2 + 1) * 2048 + (lane << 4)]);
#pragma unroll
        for (int ni = 0; ni < 2; ++ni)
            b1[ni] = ld8(&Bl[cur][((2 * cc + ni) * 2 + 1) * 2048 + (lane << 4)]);

        // ks0 MFMA cluster (counted lgkmcnt: waits only on ks0 frags)
        __builtin_amdgcn_s_setprio(1);
#pragma unroll
        for (int mi = 0; mi < 4; ++mi)
#pragma unroll
            for (int ni = 0; ni < 2; ++ni)
                acc[mi][ni] = __builtin_amdgcn_mfma_scale_f32_32x32x64_f8f6f4(
                    a0[mi], b0[ni], acc[mi][ni], 0, 0, 0, 0x7F7F7F7F, 0, 0x7F7F7F7F);
        __builtin_amdgcn_s_setprio(0);
        // ks1 MFMA cluster (its reads completed under ks0's MFMAs)
        __builtin_amdgcn_s_setprio(1);
#pragma unroll
        for (int mi = 0; mi < 4; ++mi)
#pragma unroll
            for (int ni = 0; ni < 2; ++ni)
                acc[mi][ni] = __builtin_amdgcn_mfma_scale_f32_32x32x64_f8f6f4(
                    a1[mi], b1[ni], acc[mi][ni], 0, 0, 0, 0x7F7F7F7F, 0, 0x7F7F7F7F);
        __builtin_amdgcn_s_setprio(0);

        // tile boundary: drain staging queue (vmcnt) + sync double buffers
        __syncthreads();
        cur = nb;
    }

    // epilogue: 32x32 C/D layout col=lane&31, row=(r&3)+8*(r>>2)+4*(lane>>5)
    const int orow_b = bm * 256 + g * 128 + ((lane >> 5) << 2);
    const int ocol_b = bn * 256 + cc * 64 + (lane & 31);
#pragma unroll
    for (int ni = 0; ni < 2; ++ni) {
        const int oc = ocol_b + ni * 32;
        const float bv = bias[oc];
#pragma unroll
        for (int mi = 0; mi < 4; ++mi) {
#pragma unroll
            for (int r = 0; r < 16; ++r) {
                const int orow = orow_b + mi * 32 + (r & 3) + 8 * (r >> 2);
                out[(size_t)orow * N_DIM + oc] = fp8_roundtrip(acc[mi][ni][r]) + bv;
            }
        }
    }
}

// ---- fallback (only if ws too small): 1 thread per output, exact fp32 accumulation ----
__global__ void naive_kernel(const float* __restrict__ x, const float* __restrict__ w,
                             const float* __restrict__ bias, const float* __restrict__ sp,
                             float* __restrict__ out) {
    const int ncol = blockIdx.x * blockDim.x + threadIdx.x;
    const int m = blockIdx.y;
    const float s = *sp;
    float acc = 0.f;
    for (int k = 0; k < K_DIM; ++k) {
        float q = fp8_roundtrip(fminf(fmaxf(x[(size_t)m * K_DIM + k] * s, -0.5f), 0.5f));
        acc += q * w[(size_t)ncol * K_DIM + k];
    }
    out[(size_t)m * N_DIM + ncol] = fp8_roundtrip(acc) + bias[ncol];
}

extern "C" void kernel_launch(void* const* d_in, const int* in_sizes, int n_in,
                              void* d_out, int out_size, void* d_ws, size_t ws_size,
                              hipStream_t stream) {
    const float* x     = (const float*)d_in[0];
    const float* w     = (const float*)d_in[1];
    const float* bias  = (const float*)d_in[2];
    const float* scale = (const float*)d_in[3];
    float* out = (float*)d_out;

    const size_t needA = (size_t)M_DIM * K_DIM;   // 33.5 MB fp8
    const size_t needB = (size_t)N_DIM * K_DIM;   //  8.4 MB fp8

    if (ws_size >= needA + needB) {
        unsigned char* qA = (unsigned char*)d_ws;
        unsigned char* qB = qA + needA;
        quant_pack_kernel<<<(M_DIM * K_DIM / 16) / 256, 256, 0, stream>>>(x, qA, scale);
        quant_pack_kernel<<<(N_DIM * K_DIM / 16) / 256, 256, 0, stream>>>(w, qB, nullptr);
        gemm_fp8_kernel<<<(M_DIM / 256) * (N_DIM / 256), 512, 0, stream>>>(qA, qB, bias, out);
    } else {
        dim3 g(N_DIM / 256, M_DIM);
        naive_kernel<<<g, 256, 0, stream>>>(x, w, bias, scale, out);
    }
}

// Round 8
// 202.748 us; speedup vs baseline: 3.0564x; 1.0322x over previous
//
#include <hip/hip_runtime.h>
#include <hip/hip_fp8.h>

#define M_DIM 16384
#define N_DIM 4096
#define K_DIM 2048
#define NT64  (K_DIM / 64)     // 32 K-tiles of 64
#define NSB   (K_DIM / 64)     // k-sub-blocks per 32-row block (32 rows x 64 k each)

typedef float floatx16 __attribute__((ext_vector_type(16)));
typedef int   intx4    __attribute__((ext_vector_type(4)));
typedef int   intx8    __attribute__((ext_vector_type(8)));

__device__ __forceinline__ unsigned char f32_to_fp8(float v) {
    __hip_fp8_e4m3 t(v);
    return t.__x;
}

__device__ __forceinline__ float fp8_roundtrip(float v) {
    __hip_fp8_e4m3 t(v);
    return (float)t;
}

// async global->LDS, 16B per lane. LDS dest is wave-uniform base + lane*16.
__device__ __forceinline__ void async16(const void* g, void* l) {
    __builtin_amdgcn_global_load_lds((__attribute__((address_space(1))) void*)g,
                                     (__attribute__((address_space(3))) void*)l,
                                     16, 0, 0);
}

// read a lane-linear 32B fragment: two 16B halves 1024B apart (zero-conflict)
__device__ __forceinline__ intx8 ld8(const unsigned char* p) {
    intx4 lo = *(const intx4*)(p);
    intx4 hi = *(const intx4*)(p + 1024);
    return __builtin_shufflevector(lo, hi, 0, 1, 2, 3, 4, 5, 6, 7);
}

// ---- quantize + pack into 32x32x64-MFMA fragment order (unchanged) ----
// Sub-block = 32 rows x 64 k = 2048 B. qX[rb][kt][2048], rb = m>>5, kt = k>>6.
// Lane l (r = l&31, h = l>>5) owns k-window kt*64 + h*32 .. +31, stored as
// bytes 0-15 at l*16 and bytes 16-31 at 1024 + l*16. Staging is identity
// (lane-linear 16B), fragment reads are lane-linear ds_read_b128 -> zero bank
// conflicts. A and B share this map, so any hardware-internal k permutation
// cancels in the MFMA dot product.
__global__ void quant_pack_kernel(const float* __restrict__ in,
                                  unsigned char* __restrict__ out,
                                  const float* __restrict__ sp) {
    const int p = blockIdx.x * blockDim.x + threadIdx.x;  // one 16B packed chunk
    const float s = sp ? *sp : 1.0f;
    const int c    = p & 127;            // chunk within sub-block
    const int sb   = p >> 7;
    const int kt   = sb & (NSB - 1);
    const int rb   = sb >> 5;            // log2(NSB) = 5
    const int half = c >> 6;
    const int l    = c & 63;
    const size_t m = (size_t)rb * 32 + (l & 31);
    const int   k0 = kt * 64 + (l >> 5) * 32 + half * 16;
    const float* src = in + m * K_DIM + k0;
    float f[16];
    *(float4*)(f)      = *(const float4*)(src);
    *(float4*)(f + 4)  = *(const float4*)(src + 4);
    *(float4*)(f + 8)  = *(const float4*)(src + 8);
    *(float4*)(f + 12) = *(const float4*)(src + 12);
    unsigned long long lo = 0, hi = 0;
#pragma unroll
    for (int j = 0; j < 8; ++j) {
        float v0 = fminf(fmaxf(f[j] * s, -0.5f), 0.5f);
        float v1 = fminf(fmaxf(f[j + 8] * s, -0.5f), 0.5f);
        lo |= (unsigned long long)f32_to_fp8(v0) << (8 * j);
        hi |= (unsigned long long)f32_to_fp8(v1) << (8 * j);
    }
    unsigned long long* dst = (unsigned long long*)(out + (size_t)p * 16);
    dst[0] = lo;
    dst[1] = hi;
}

// stage one BK=64 tile slice (wave wid's 32-row A block + 32-col B block)
#define STAGE(s_, t_) do {                                                  \
    const size_t go_ = (size_t)(t_) * 2048;                                 \
    async16(gAw + go_,        &Al[(s_)][wid * 2048]);                       \
    async16(gAw + go_ + 1024, &Al[(s_)][wid * 2048 + 1024]);                \
    async16(gBw + go_,        &Bl[(s_)][wid * 2048]);                       \
    async16(gBw + go_ + 1024, &Bl[(s_)][wid * 2048 + 1024]);                \
} while (0)

// one K=64 tile: counted vmcnt (T4: never 0 in steady state), ONE raw barrier,
// lane-linear ds_reads, stage t+3, setprio'd MFMA cluster.
#define TILE(t_, VM_, ST_) do {                                             \
    asm volatile("s_waitcnt vmcnt(" VM_ ")" ::: "memory");                  \
    __builtin_amdgcn_s_barrier();                                           \
    const int s_ = (t_) & 3;                                                \
    intx8 a_[4], b_[2];                                                     \
    _Pragma("unroll")                                                       \
    for (int mi = 0; mi < 4; ++mi)                                          \
        a_[mi] = ld8(&Al[s_][(4 * g + mi) * 2048 + (lane << 4)]);           \
    _Pragma("unroll")                                                       \
    for (int ni = 0; ni < 2; ++ni)                                          \
        b_[ni] = ld8(&Bl[s_][(2 * cc + ni) * 2048 + (lane << 4)]);          \
    if (ST_) STAGE(((t_) + 3) & 3, (t_) + 3);                               \
    __builtin_amdgcn_s_setprio(1);                                          \
    _Pragma("unroll")                                                       \
    for (int mi = 0; mi < 4; ++mi)                                          \
        _Pragma("unroll")                                                   \
        for (int ni = 0; ni < 2; ++ni)                                      \
            acc[mi][ni] = __builtin_amdgcn_mfma_scale_f32_32x32x64_f8f6f4(  \
                a_[mi], b_[ni], acc[mi][ni], 0, 0, 0, 0x7F7F7F7F, 0, 0x7F7F7F7F); \
    __builtin_amdgcn_s_setprio(0);                                          \
} while (0)

// ---- MX-fp8 GEMM: 256x256 tile, BK=64, 8 waves (2Mx4N), 32x32x64 scaled MFMA ----
// 4-deep LDS stage ring, staged 3 tiles ahead; per tile ONE counted vmcnt +
// ONE raw s_barrier (no full drain in the main loop).
// Ring correctness: RAW -- wave's vmcnt(8) before the barrier proves its own
// stage-t landed; barrier collects all waves. WAR -- stage t+3 overwrites the
// buffer last read at t-1; every wave's t-1 reads completed (lgkm-waited by
// its t-1 MFMAs) before it reached this barrier.
// Scales fixed at e8m0 1.0 (0x7F) -> numerically identical to plain fp8 GEMM.
__global__ __launch_bounds__(512, 1) void gemm_fp8_kernel(
        const unsigned char* __restrict__ qA, const unsigned char* __restrict__ qB,
        const float* __restrict__ bias, float* __restrict__ out) {
    __shared__ unsigned char Al[4][8 * 2048];   // 4 stages x 16 KB (256 rows x 64 k)
    __shared__ unsigned char Bl[4][8 * 2048];   // 4 stages x 16 KB

    const int tid  = threadIdx.x;
    const int lane = tid & 63;
    const int wid  = tid >> 6;           // 0..7

    // XCD-aware swizzle: 1024 blocks % 8 == 0 -> bijective simple form
    const int cpx = gridDim.x >> 3;
    const int swz = (blockIdx.x & 7) * cpx + (blockIdx.x >> 3);
    const int bm = swz & 63;             // M/256 = 64 tiles
    const int bn = swz >> 6;             // N/256 = 16 tiles

    // staging: wave wid owns A row-block (bm*8+wid) / B col-block (bn*8+wid);
    // row-block stride = NSB*2048 = 64 KB; per-tile offset = t*2048.
    const unsigned char* gAw = qA + ((size_t)(bm * 8 + wid) << 16) + (lane << 4);
    const unsigned char* gBw = qB + ((size_t)(bn * 8 + wid) << 16) + (lane << 4);

    // compute: wave (g = wid>>2, cc = wid&3) owns a 128x64 output sub-tile
    const int g  = wid >> 2;
    const int cc = wid & 3;

    floatx16 acc[4][2] = {};             // 4 row-blocks x 2 col-blocks of 32x32

    // ---- prologue: stage tiles 0,1,2 (12 loads/wave outstanding) ----
#pragma unroll
    for (int s = 0; s < 3; ++s) STAGE(s, s);

    // ---- main loop: steady-state vmcnt(8) = stages t+1,t+2 stay in flight ----
    for (int t = 0; t < NT64 - 3; ++t) {
        TILE(t, "8", 1);
    }
    // ---- epilogue peel: ring drains 8 -> 4 -> 0 ----
    TILE(NT64 - 3, "8", 0);
    TILE(NT64 - 2, "4", 0);
    TILE(NT64 - 1, "0", 0);

    // epilogue: 32x32 C/D layout col=lane&31, row=(r&3)+8*(r>>2)+4*(lane>>5)
    const int orow_b = bm * 256 + g * 128 + ((lane >> 5) << 2);
    const int ocol_b = bn * 256 + cc * 64 + (lane & 31);
#pragma unroll
    for (int ni = 0; ni < 2; ++ni) {
        const int oc = ocol_b + ni * 32;
        const float bv = bias[oc];
#pragma unroll
        for (int mi = 0; mi < 4; ++mi) {
#pragma unroll
            for (int r = 0; r < 16; ++r) {
                const int orow = orow_b + mi * 32 + (r & 3) + 8 * (r >> 2);
                out[(size_t)orow * N_DIM + oc] = fp8_roundtrip(acc[mi][ni][r]) + bv;
            }
        }
    }
}

// ---- fallback (only if ws too small): 1 thread per output, exact fp32 accumulation ----
__global__ void naive_kernel(const float* __restrict__ x, const float* __restrict__ w,
                             const float* __restrict__ bias, const float* __restrict__ sp,
                             float* __restrict__ out) {
    const int ncol = blockIdx.x * blockDim.x + threadIdx.x;
    const int m = blockIdx.y;
    const float s = *sp;
    float acc = 0.f;
    for (int k = 0; k < K_DIM; ++k) {
        float q = fp8_roundtrip(fminf(fmaxf(x[(size_t)m * K_DIM + k] * s, -0.5f), 0.5f));
        acc += q * w[(size_t)ncol * K_DIM + k];
    }
    out[(size_t)m * N_DIM + ncol] = fp8_roundtrip(acc) + bias[ncol];
}

extern "C" void kernel_launch(void* const* d_in, const int* in_sizes, int n_in,
                              void* d_out, int out_size, void* d_ws, size_t ws_size,
                              hipStream_t stream) {
    const float* x     = (const float*)d_in[0];
    const float* w     = (const float*)d_in[1];
    const float* bias  = (const float*)d_in[2];
    const float* scale = (const float*)d_in[3];
    float* out = (float*)d_out;

    const size_t needA = (size_t)M_DIM * K_DIM;   // 33.5 MB fp8
    const size_t needB = (size_t)N_DIM * K_DIM;   //  8.4 MB fp8

    if (ws_size >= needA + needB) {
        unsigned char* qA = (unsigned char*)d_ws;
        unsigned char* qB = qA + needA;
        quant_pack_kernel<<<(M_DIM * K_DIM / 16) / 256, 256, 0, stream>>>(x, qA, scale);
        quant_pack_kernel<<<(N_DIM * K_DIM / 16) / 256, 256, 0, stream>>>(w, qB, nullptr);
        gemm_fp8_kernel<<<(M_DIM / 256) * (N_DIM / 256), 512, 0, stream>>>(qA, qB, bias, out);
    } else {
        dim3 g(N_DIM / 256, M_DIM);
        naive_kernel<<<g, 256, 0, stream>>>(x, w, bias, scale, out);
    }
}

// Round 9
// 199.180 us; speedup vs baseline: 3.1111x; 1.0179x over previous
//
#include <hip/hip_runtime.h>
#include <hip/hip_fp8.h>

#define M_DIM 16384
#define N_DIM 4096
#define K_DIM 2048
#define NT64  (K_DIM / 64)     // 32 K-tiles of 64
#define NSB   (K_DIM / 64)     // k-sub-blocks per 32-row block (32 rows x 64 k each)

typedef float floatx16 __attribute__((ext_vector_type(16)));
typedef int   intx4    __attribute__((ext_vector_type(4)));
typedef int   intx8    __attribute__((ext_vector_type(8)));

__device__ __forceinline__ unsigned char f32_to_fp8(float v) {
    __hip_fp8_e4m3 t(v);
    return t.__x;
}

__device__ __forceinline__ float fp8_roundtrip(float v) {
    __hip_fp8_e4m3 t(v);
    return (float)t;
}

// async global->LDS, 16B per lane. LDS dest is wave-uniform base + lane*16.
__device__ __forceinline__ void async16(const void* g, void* l) {
    __builtin_amdgcn_global_load_lds((__attribute__((address_space(1))) void*)g,
                                     (__attribute__((address_space(3))) void*)l,
                                     16, 0, 0);
}

// read a lane-linear 32B fragment: two 16B halves 1024B apart (zero-conflict)
__device__ __forceinline__ intx8 ld8(const unsigned char* p) {
    intx4 lo = *(const intx4*)(p);
    intx4 hi = *(const intx4*)(p + 1024);
    return __builtin_shufflevector(lo, hi, 0, 1, 2, 3, 4, 5, 6, 7);
}

// ---- quantize + pack into 32x32x64-MFMA fragment order (unchanged) ----
// Sub-block = 32 rows x 64 k = 2048 B. qX[rb][kt][2048], rb = m>>5, kt = k>>6.
// Lane l (r = l&31, h = l>>5) owns k-window kt*64 + h*32 .. +31, stored as
// bytes 0-15 at l*16 and bytes 16-31 at 1024 + l*16. Staging is identity
// (lane-linear 16B), fragment reads are lane-linear ds_read_b128 -> zero bank
// conflicts. A and B share this map, so any hardware-internal k permutation
// cancels in the MFMA dot product.
__global__ void quant_pack_kernel(const float* __restrict__ in,
                                  unsigned char* __restrict__ out,
                                  const float* __restrict__ sp) {
    const int p = blockIdx.x * blockDim.x + threadIdx.x;  // one 16B packed chunk
    const float s = sp ? *sp : 1.0f;
    const int c    = p & 127;            // chunk within sub-block
    const int sb   = p >> 7;
    const int kt   = sb & (NSB - 1);
    const int rb   = sb >> 5;            // log2(NSB) = 5
    const int half = c >> 6;
    const int l    = c & 63;
    const size_t m = (size_t)rb * 32 + (l & 31);
    const int   k0 = kt * 64 + (l >> 5) * 32 + half * 16;
    const float* src = in + m * K_DIM + k0;
    float f[16];
    *(float4*)(f)      = *(const float4*)(src);
    *(float4*)(f + 4)  = *(const float4*)(src + 4);
    *(float4*)(f + 8)  = *(const float4*)(src + 8);
    *(float4*)(f + 12) = *(const float4*)(src + 12);
    unsigned long long lo = 0, hi = 0;
#pragma unroll
    for (int j = 0; j < 8; ++j) {
        float v0 = fminf(fmaxf(f[j] * s, -0.5f), 0.5f);
        float v1 = fminf(fmaxf(f[j + 8] * s, -0.5f), 0.5f);
        lo |= (unsigned long long)f32_to_fp8(v0) << (8 * j);
        hi |= (unsigned long long)f32_to_fp8(v1) << (8 * j);
    }
    unsigned long long* dst = (unsigned long long*)(out + (size_t)p * 16);
    dst[0] = lo;
    dst[1] = hi;
}

#define MF(A_, B_, C_) (C_) = __builtin_amdgcn_mfma_scale_f32_32x32x64_f8f6f4( \
        (A_), (B_), (C_), 0, 0, 0, 0x7F7F7F7F, 0, 0x7F7F7F7F)

// stage one BK=64 tile slice (wave wid's 32-row A block + 32-col B block)
#define STAGE(s_, t_) do {                                                  \
    const size_t go_ = (size_t)(t_) * 2048;                                 \
    async16(gAw + go_,        &Al[(s_)][wid * 2048]);                       \
    async16(gAw + go_ + 1024, &Al[(s_)][wid * 2048 + 1024]);                \
    async16(gBw + go_,        &Bl[(s_)][wid * 2048]);                       \
    async16(gBw + go_ + 1024, &Bl[(s_)][wid * 2048 + 1024]);                \
} while (0)

// One K=64 tile, cross-tile pipelined: UA = A-frags for THIS tile (read last
// tile); NA = A-frags for NEXT tile, read in sub-phases interleaved between
// this tile's MFMA pairs (pinned by sched_barrier(0) so the compiler can't
// sink them back into a burst). B is single-buffered, read at tile head.
// vmcnt(4) at head proves stage t (B-current) AND stage t+1 (A-ahead) landed
// for this wave; the s_barrier extends that to all waves' staging.
#define TILE(UA, NA, t_, VM_, ST_, RA_) do {                                \
    asm volatile("s_waitcnt vmcnt(" VM_ ")" ::: "memory");                  \
    __builtin_amdgcn_s_barrier();                                           \
    const int sc_ = (t_) & 3;                                               \
    const int sn_ = ((t_) + 1) & 3;                                         \
    __builtin_amdgcn_s_setprio(1);                                          \
    fb[0] = ld8(&Bl[sc_][(2 * cc + 0) * 2048 + (lane << 4)]);               \
    fb[1] = ld8(&Bl[sc_][(2 * cc + 1) * 2048 + (lane << 4)]);               \
    if (RA_) { NA[0] = ld8(&Al[sn_][(4 * g + 0) * 2048 + (lane << 4)]);     \
               NA[1] = ld8(&Al[sn_][(4 * g + 1) * 2048 + (lane << 4)]); }   \
    MF(UA[0], fb[0], acc[0][0]); MF(UA[0], fb[1], acc[0][1]);               \
    __builtin_amdgcn_sched_barrier(0);                                      \
    if (RA_) { NA[2] = ld8(&Al[sn_][(4 * g + 2) * 2048 + (lane << 4)]);     \
               NA[3] = ld8(&Al[sn_][(4 * g + 3) * 2048 + (lane << 4)]); }   \
    MF(UA[1], fb[0], acc[1][0]); MF(UA[1], fb[1], acc[1][1]);               \
    __builtin_amdgcn_sched_barrier(0);                                      \
    if (ST_) STAGE(((t_) + 3) & 3, (t_) + 3);                               \
    MF(UA[2], fb[0], acc[2][0]); MF(UA[2], fb[1], acc[2][1]);               \
    __builtin_amdgcn_sched_barrier(0);                                      \
    MF(UA[3], fb[0], acc[3][0]); MF(UA[3], fb[1], acc[3][1]);               \
    __builtin_amdgcn_s_setprio(0);                                          \
} while (0)

// ---- MX-fp8 GEMM: 256x256 tile, BK=64, 8 waves (2Mx4N), 32x32x64 scaled MFMA ----
// 4-deep LDS stage ring staged 3 ahead (counted vmcnt, one s_barrier/tile) +
// cross-tile A-fragment read-ahead interleaved into the MFMA stream.
// Ring: RAW -- vmcnt(4)+barrier at head of t proves stages t, t+1 landed for
// all waves. WAR -- STAGE(t+3) overwrites buffer (t-1)&3, whose reads (issued
// at t-2) completed before each wave's t-1 MFMAs, hence before barrier t.
// Scales fixed at e8m0 1.0 (0x7F) -> numerically identical to plain fp8 GEMM.
__global__ __launch_bounds__(512, 1) void gemm_fp8_kernel(
        const unsigned char* __restrict__ qA, const unsigned char* __restrict__ qB,
        const float* __restrict__ bias, float* __restrict__ out) {
    __shared__ unsigned char Al[4][8 * 2048];   // 4 stages x 16 KB (256 rows x 64 k)
    __shared__ unsigned char Bl[4][8 * 2048];   // 4 stages x 16 KB

    const int tid  = threadIdx.x;
    const int lane = tid & 63;
    const int wid  = tid >> 6;           // 0..7

    // XCD-aware swizzle: 1024 blocks % 8 == 0 -> bijective simple form
    const int cpx = gridDim.x >> 3;
    const int swz = (blockIdx.x & 7) * cpx + (blockIdx.x >> 3);
    const int bm = swz & 63;             // M/256 = 64 tiles
    const int bn = swz >> 6;             // N/256 = 16 tiles

    // staging: wave wid owns A row-block (bm*8+wid) / B col-block (bn*8+wid);
    // row-block stride = NSB*2048 = 64 KB; per-tile offset = t*2048.
    const unsigned char* gAw = qA + ((size_t)(bm * 8 + wid) << 16) + (lane << 4);
    const unsigned char* gBw = qB + ((size_t)(bn * 8 + wid) << 16) + (lane << 4);

    // compute: wave (g = wid>>2, cc = wid&3) owns a 128x64 output sub-tile
    const int g  = wid >> 2;
    const int cc = wid & 3;

    floatx16 acc[4][2] = {};             // 4 row-blocks x 2 col-blocks of 32x32
    intx8 fa[4], ga[4], fb[2];           // A frag double-buffer + B single

    // ---- prologue: stage tiles 0,1,2; read A-frags for tile 0 ----
#pragma unroll
    for (int s = 0; s < 3; ++s) STAGE(s, s);
    asm volatile("s_waitcnt vmcnt(8)" ::: "memory");   // stage 0 landed (own)
    __builtin_amdgcn_s_barrier();                      // ... for all waves
#pragma unroll
    for (int mi = 0; mi < 4; ++mi)
        fa[mi] = ld8(&Al[0][(4 * g + mi) * 2048 + (lane << 4)]);

    // ---- main loop (unrolled x2 for frag-set parity) ----
    for (int t = 0; t < NT64 - 4; t += 2) {
        TILE(fa, ga, t,     "4", 1, 1);
        TILE(ga, fa, t + 1, "4", 1, 1);
    }
    // ---- tail: t = 28..31 (stages 31 issued at t=28; ring drains) ----
    TILE(fa, ga, NT64 - 4, "4", 1, 1);
    TILE(ga, fa, NT64 - 3, "4", 0, 1);
    TILE(fa, ga, NT64 - 2, "0", 0, 1);
    TILE(ga, fa, NT64 - 1, "0", 0, 0);

    // epilogue: 32x32 C/D layout col=lane&31, row=(r&3)+8*(r>>2)+4*(lane>>5)
    const int orow_b = bm * 256 + g * 128 + ((lane >> 5) << 2);
    const int ocol_b = bn * 256 + cc * 64 + (lane & 31);
#pragma unroll
    for (int ni = 0; ni < 2; ++ni) {
        const int oc = ocol_b + ni * 32;
        const float bv = bias[oc];
#pragma unroll
        for (int mi = 0; mi < 4; ++mi) {
#pragma unroll
            for (int r = 0; r < 16; ++r) {
                const int orow = orow_b + mi * 32 + (r & 3) + 8 * (r >> 2);
                out[(size_t)orow * N_DIM + oc] = fp8_roundtrip(acc[mi][ni][r]) + bv;
            }
        }
    }
}

// ---- fallback (only if ws too small): 1 thread per output, exact fp32 accumulation ----
__global__ void naive_kernel(const float* __restrict__ x, const float* __restrict__ w,
                             const float* __restrict__ bias, const float* __restrict__ sp,
                             float* __restrict__ out) {
    const int ncol = blockIdx.x * blockDim.x + threadIdx.x;
    const int m = blockIdx.y;
    const float s = *sp;
    float acc = 0.f;
    for (int k = 0; k < K_DIM; ++k) {
        float q = fp8_roundtrip(fminf(fmaxf(x[(size_t)m * K_DIM + k] * s, -0.5f), 0.5f));
        acc += q * w[(size_t)ncol * K_DIM + k];
    }
    out[(size_t)m * N_DIM + ncol] = fp8_roundtrip(acc) + bias[ncol];
}

extern "C" void kernel_launch(void* const* d_in, const int* in_sizes, int n_in,
                              void* d_out, int out_size, void* d_ws, size_t ws_size,
                              hipStream_t stream) {
    const float* x     = (const float*)d_in[0];
    const float* w     = (const float*)d_in[1];
    const float* bias  = (const float*)d_in[2];
    const float* scale = (const float*)d_in[3];
    float* out = (float*)d_out;

    const size_t needA = (size_t)M_DIM * K_DIM;   // 33.5 MB fp8
    const size_t needB = (size_t)N_DIM * K_DIM;   //  8.4 MB fp8

    if (ws_size >= needA + needB) {
        unsigned char* qA = (unsigned char*)d_ws;
        unsigned char* qB = qA + needA;
        quant_pack_kernel<<<(M_DIM * K_DIM / 16) / 256, 256, 0, stream>>>(x, qA, scale);
        quant_pack_kernel<<<(N_DIM * K_DIM / 16) / 256, 256, 0, stream>>>(w, qB, nullptr);
        gemm_fp8_kernel<<<(M_DIM / 256) * (N_DIM / 256), 512, 0, stream>>>(qA, qB, bias, out);
    } else {
        dim3 g(N_DIM / 256, M_DIM);
        naive_kernel<<<g, 256, 0, stream>>>(x, w, bias, scale, out);
    }
}

// Round 10
// 198.753 us; speedup vs baseline: 3.1178x; 1.0021x over previous
//
#include <hip/hip_runtime.h>
#include <hip/hip_fp8.h>

#define M_DIM 16384
#define N_DIM 4096
#define K_DIM 2048
#define NT64  (K_DIM / 64)     // 32 K-tiles of 64
#define NSB   (K_DIM / 64)     // k-sub-blocks per 32-row block (32 rows x 64 k each)

typedef float floatx16 __attribute__((ext_vector_type(16)));
typedef int   intx4    __attribute__((ext_vector_type(4)));
typedef int   intx8    __attribute__((ext_vector_type(8)));

__device__ __forceinline__ unsigned char f32_to_fp8(float v) {
    __hip_fp8_e4m3 t(v);
    return t.__x;
}

__device__ __forceinline__ float fp8_roundtrip(float v) {
    __hip_fp8_e4m3 t(v);
    return (float)t;
}

// async global->LDS, 16B per lane. LDS dest is wave-uniform base + lane*16.
__device__ __forceinline__ void async16(const void* g, void* l) {
    __builtin_amdgcn_global_load_lds((__attribute__((address_space(1))) void*)g,
                                     (__attribute__((address_space(3))) void*)l,
                                     16, 0, 0);
}

// read a lane-linear 32B fragment: two 16B halves 1024B apart (zero-conflict)
__device__ __forceinline__ intx8 ld8(const unsigned char* p) {
    intx4 lo = *(const intx4*)(p);
    intx4 hi = *(const intx4*)(p + 1024);
    return __builtin_shufflevector(lo, hi, 0, 1, 2, 3, 4, 5, 6, 7);
}

// ---- quantize + pack into 32x32x64-MFMA fragment order (unchanged) ----
// Sub-block = 32 rows x 64 k = 2048 B. qX[rb][kt][2048], rb = m>>5, kt = k>>6.
// Lane l (r = l&31, h = l>>5) owns k-window kt*64 + h*32 .. +31, stored as
// bytes 0-15 at l*16 and bytes 16-31 at 1024 + l*16. Staging is identity
// (lane-linear 16B), fragment reads are lane-linear ds_read_b128 -> zero bank
// conflicts. A and B share this map, so any hardware-internal k permutation
// cancels in the MFMA dot product.
__global__ void quant_pack_kernel(const float* __restrict__ in,
                                  unsigned char* __restrict__ out,
                                  const float* __restrict__ sp) {
    const int p = blockIdx.x * blockDim.x + threadIdx.x;  // one 16B packed chunk
    const float s = sp ? *sp : 1.0f;
    const int c    = p & 127;            // chunk within sub-block
    const int sb   = p >> 7;
    const int kt   = sb & (NSB - 1);
    const int rb   = sb >> 5;            // log2(NSB) = 5
    const int half = c >> 6;
    const int l    = c & 63;
    const size_t m = (size_t)rb * 32 + (l & 31);
    const int   k0 = kt * 64 + (l >> 5) * 32 + half * 16;
    const float* src = in + m * K_DIM + k0;
    float f[16];
    *(float4*)(f)      = *(const float4*)(src);
    *(float4*)(f + 4)  = *(const float4*)(src + 4);
    *(float4*)(f + 8)  = *(const float4*)(src + 8);
    *(float4*)(f + 12) = *(const float4*)(src + 12);
    unsigned long long lo = 0, hi = 0;
#pragma unroll
    for (int j = 0; j < 8; ++j) {
        float v0 = fminf(fmaxf(f[j] * s, -0.5f), 0.5f);
        float v1 = fminf(fmaxf(f[j + 8] * s, -0.5f), 0.5f);
        lo |= (unsigned long long)f32_to_fp8(v0) << (8 * j);
        hi |= (unsigned long long)f32_to_fp8(v1) << (8 * j);
    }
    unsigned long long* dst = (unsigned long long*)(out + (size_t)p * 16);
    dst[0] = lo;
    dst[1] = hi;
}

#define MF(A_, B_, C_) (C_) = __builtin_amdgcn_mfma_scale_f32_32x32x64_f8f6f4( \
        (A_), (B_), (C_), 0, 0, 0, 0x7F7F7F7F, 0, 0x7F7F7F7F)

// stage one BK=64 tile slice (wave wid's 32-row A block + 32-col B block)
#define STAGE(s_, t_) do {                                                  \
    const size_t go_ = (size_t)(t_) * 2048;                                 \
    async16(gAw + go_,        &Al[(s_)][wid * 2048]);                       \
    async16(gAw + go_ + 1024, &Al[(s_)][wid * 2048 + 1024]);                \
    async16(gBw + go_,        &Bl[(s_)][wid * 2048]);                       \
    async16(gBw + go_ + 1024, &Bl[(s_)][wid * 2048 + 1024]);                \
} while (0)

// One K=64 tile. INVARIANT: all 8 MFMA operands of this tile are in registers
// BEFORE the head barrier (ANc = A0,A1 + BNc = B0,B1 read cross-tile; aL =
// A2,A3 read in-tile at gap0, used 2 MFMA-pairs later). So pair0 issues
// immediately after the barrier and every ds_read/stage rides under the MFMA
// stream in sched_barrier-pinned gaps. One counted vmcnt + one s_barrier/tile.
#define TILE(ANc, ANn, BNc, BNn, t_, VM_, ST_, RA_) do {                    \
    asm volatile("s_waitcnt vmcnt(" VM_ ")" ::: "memory");                  \
    __builtin_amdgcn_s_barrier();                                           \
    const int sc_ = (t_) & 3;                                               \
    const int sn_ = ((t_) + 1) & 3;                                         \
    __builtin_amdgcn_s_setprio(1);                                          \
    MF(ANc[0], BNc[0], acc[0][0]); MF(ANc[0], BNc[1], acc[0][1]);           \
    __builtin_amdgcn_sched_barrier(0);                                      \
    aL[0] = ld8(&Al[sc_][(4 * g + 2) * 2048 + (lane << 4)]);                \
    aL[1] = ld8(&Al[sc_][(4 * g + 3) * 2048 + (lane << 4)]);                \
    if (ST_) STAGE(((t_) + 3) & 3, (t_) + 3);                               \
    MF(ANc[1], BNc[0], acc[1][0]); MF(ANc[1], BNc[1], acc[1][1]);           \
    __builtin_amdgcn_sched_barrier(0);                                      \
    if (RA_) { BNn[0] = ld8(&Bl[sn_][(2 * cc + 0) * 2048 + (lane << 4)]);   \
               BNn[1] = ld8(&Bl[sn_][(2 * cc + 1) * 2048 + (lane << 4)]); } \
    MF(aL[0], BNc[0], acc[2][0]); MF(aL[0], BNc[1], acc[2][1]);             \
    __builtin_amdgcn_sched_barrier(0);                                      \
    if (RA_) { ANn[0] = ld8(&Al[sn_][(4 * g + 0) * 2048 + (lane << 4)]);    \
               ANn[1] = ld8(&Al[sn_][(4 * g + 1) * 2048 + (lane << 4)]); }  \
    MF(aL[1], BNc[0], acc[3][0]); MF(aL[1], BNc[1], acc[3][1]);             \
    __builtin_amdgcn_s_setprio(0);                                          \
} while (0)

// ---- MX-fp8 GEMM: 256x256 tile, BK=64, 8 waves (2Mx4N), 32x32x64 scaled MFMA ----
// 4-deep LDS stage ring staged 3 ahead; all-register tile heads.
// Ring: RAW -- vmcnt(4)+barrier at head of t proves stage t+1 landed for all
// waves (stage t+2's 4 loads are the only newer vmem). WAR -- STAGE(t+3)
// overwrites buffer (t-1)&3, whose reads retired before each wave's t-1 MFMAs,
// hence before barrier t. Scales e8m0 1.0 (0x7F) -> identical to plain fp8.
__global__ __launch_bounds__(512, 1) void gemm_fp8_kernel(
        const unsigned char* __restrict__ qA, const unsigned char* __restrict__ qB,
        const float* __restrict__ bias, float* __restrict__ out) {
    __shared__ unsigned char Al[4][8 * 2048];   // 4 stages x 16 KB (256 rows x 64 k)
    __shared__ unsigned char Bl[4][8 * 2048];   // 4 stages x 16 KB

    const int tid  = threadIdx.x;
    const int lane = tid & 63;
    const int wid  = tid >> 6;           // 0..7

    // XCD-aware swizzle: 1024 blocks % 8 == 0 -> bijective simple form
    const int cpx = gridDim.x >> 3;
    const int swz = (blockIdx.x & 7) * cpx + (blockIdx.x >> 3);
    const int bm = swz & 63;             // M/256 = 64 tiles
    const int bn = swz >> 6;             // N/256 = 16 tiles

    // staging: wave wid owns A row-block (bm*8+wid) / B col-block (bn*8+wid);
    // row-block stride = NSB*2048 = 64 KB; per-tile offset = t*2048.
    const unsigned char* gAw = qA + ((size_t)(bm * 8 + wid) << 16) + (lane << 4);
    const unsigned char* gBw = qB + ((size_t)(bn * 8 + wid) << 16) + (lane << 4);

    // compute: wave (g = wid>>2, cc = wid&3) owns a 128x64 output sub-tile
    const int g  = wid >> 2;
    const int cc = wid & 3;

    floatx16 acc[4][2] = {};             // 4 row-blocks x 2 col-blocks of 32x32
    intx8 aX[2], aY[2], bX[2], bY[2], aL[2];   // cross-tile A0,A1 / B0,B1 + in-tile A2,A3

    // ---- prologue: stage tiles 0,1,2; read tile-0's A0,A1,B0,B1 ----
#pragma unroll
    for (int s = 0; s < 3; ++s) STAGE(s, s);
    asm volatile("s_waitcnt vmcnt(8)" ::: "memory");   // stage 0 landed (own)
    __builtin_amdgcn_s_barrier();                      // ... for all waves
    aX[0] = ld8(&Al[0][(4 * g + 0) * 2048 + (lane << 4)]);
    aX[1] = ld8(&Al[0][(4 * g + 1) * 2048 + (lane << 4)]);
    bX[0] = ld8(&Bl[0][(2 * cc + 0) * 2048 + (lane << 4)]);
    bX[1] = ld8(&Bl[0][(2 * cc + 1) * 2048 + (lane << 4)]);

    // ---- main loop (unrolled x2 for frag-set parity) ----
    for (int t = 0; t < NT64 - 4; t += 2) {
        TILE(aX, aY, bX, bY, t,     "4", 1, 1);
        TILE(aY, aX, bY, bX, t + 1, "4", 1, 1);
    }
    // ---- tail: t = 28..31 (last stage st31 issued at t=28; ring drains) ----
    TILE(aX, aY, bX, bY, NT64 - 4, "4", 1, 1);
    TILE(aY, aX, bY, bX, NT64 - 3, "4", 0, 1);
    TILE(aX, aY, bX, bY, NT64 - 2, "0", 0, 1);
    TILE(aY, aX, bY, bX, NT64 - 1, "0", 0, 0);

    // epilogue: 32x32 C/D layout col=lane&31, row=(r&3)+8*(r>>2)+4*(lane>>5);
    // non-temporal stores keep the 262 MB output stream from thrashing L3.
    const int orow_b = bm * 256 + g * 128 + ((lane >> 5) << 2);
    const int ocol_b = bn * 256 + cc * 64 + (lane & 31);
#pragma unroll
    for (int ni = 0; ni < 2; ++ni) {
        const int oc = ocol_b + ni * 32;
        const float bv = bias[oc];
#pragma unroll
        for (int mi = 0; mi < 4; ++mi) {
#pragma unroll
            for (int r = 0; r < 16; ++r) {
                const int orow = orow_b + mi * 32 + (r & 3) + 8 * (r >> 2);
                __builtin_nontemporal_store(fp8_roundtrip(acc[mi][ni][r]) + bv,
                                            &out[(size_t)orow * N_DIM + oc]);
            }
        }
    }
}

// ---- fallback (only if ws too small): 1 thread per output, exact fp32 accumulation ----
__global__ void naive_kernel(const float* __restrict__ x, const float* __restrict__ w,
                             const float* __restrict__ bias, const float* __restrict__ sp,
                             float* __restrict__ out) {
    const int ncol = blockIdx.x * blockDim.x + threadIdx.x;
    const int m = blockIdx.y;
    const float s = *sp;
    float acc = 0.f;
    for (int k = 0; k < K_DIM; ++k) {
        float q = fp8_roundtrip(fminf(fmaxf(x[(size_t)m * K_DIM + k] * s, -0.5f), 0.5f));
        acc += q * w[(size_t)ncol * K_DIM + k];
    }
    out[(size_t)m * N_DIM + ncol] = fp8_roundtrip(acc) + bias[ncol];
}

extern "C" void kernel_launch(void* const* d_in, const int* in_sizes, int n_in,
                              void* d_out, int out_size, void* d_ws, size_t ws_size,
                              hipStream_t stream) {
    const float* x     = (const float*)d_in[0];
    const float* w     = (const float*)d_in[1];
    const float* bias  = (const float*)d_in[2];
    const float* scale = (const float*)d_in[3];
    float* out = (float*)d_out;

    const size_t needA = (size_t)M_DIM * K_DIM;   // 33.5 MB fp8
    const size_t needB = (size_t)N_DIM * K_DIM;   //  8.4 MB fp8

    if (ws_size >= needA + needB) {
        unsigned char* qA = (unsigned char*)d_ws;
        unsigned char* qB = qA + needA;
        quant_pack_kernel<<<(M_DIM * K_DIM / 16) / 256, 256, 0, stream>>>(x, qA, scale);
        quant_pack_kernel<<<(N_DIM * K_DIM / 16) / 256, 256, 0, stream>>>(w, qB, nullptr);
        gemm_fp8_kernel<<<(M_DIM / 256) * (N_DIM / 256), 512, 0, stream>>>(qA, qB, bias, out);
    } else {
        dim3 g(N_DIM / 256, M_DIM);
        naive_kernel<<<g, 256, 0, stream>>>(x, w, bias, scale, out);
    }
}